// Round 15
// baseline (4263.100 us; speedup 1.0000x reference)
//
#include <hip/hip_runtime.h>

#define VOCAB 32000
#define EMBD  512
#define HIDD  1024
#define SLEN  512
#define NBAT  4
#define GATE4 4096   // 4*HIDD
#define ABLK  128    // layer-0 blocks, 8 units each
#define BBLK  128    // layer-1 blocks, 8 units each (Wk1 in LDS, Wr1 in regs)

typedef unsigned long long u64;

#define AL(p) __hip_atomic_load((p), __ATOMIC_RELAXED, __HIP_MEMORY_SCOPE_AGENT)
#define AS(p, v) __hip_atomic_store((p), (v), __ATOMIC_RELAXED, __HIP_MEMORY_SCOPE_AGENT)

// ---------------- 32x32 tiled transpose: [1024][4096] -> [4096][1024] -------
__global__ __launch_bounds__(256) void transpose_k(const float* __restrict__ src,
                                                   float* __restrict__ dst) {
  __shared__ float t[32][33];
  const int bx = blockIdx.x * 32;
  const int by = blockIdx.y * 32;
  const int r0 = threadIdx.x >> 5;
  const int c  = threadIdx.x & 31;
  #pragma unroll
  for (int i = 0; i < 4; i++) {
    const int r = r0 + i*8;
    t[r][c] = src[(size_t)(by + r)*GATE4 + bx + c];
  }
  __syncthreads();
  #pragma unroll
  for (int i = 0; i < 4; i++) {
    const int rw = r0 + i*8;
    dst[(size_t)(bx + rw)*HIDD + by + c] = t[c][rw];
  }
}

// -------- layer-0 input GEMM with fused embedding gather:
// Z[m][n] = sum_k emb[ids[m]][k] * Wk0[k][n] + b0[n]   (M=2048,N=4096,K=512)
__global__ __launch_bounds__(256) void gemm_nn_emb(
    const int* __restrict__ ids, const float* __restrict__ emb,
    const float* __restrict__ B, const float* __restrict__ bias,
    float* __restrict__ C, int N, int K) {
  __shared__ float As[16][64];
  __shared__ float Bs[16][64];
  const int tid = threadIdx.x;
  const int bm = blockIdx.y * 64;
  const int bn = blockIdx.x * 64;
  const int tx = tid & 15, ty = tid >> 4;
  const int mA = tid >> 2, kqA = (tid & 3) * 4;
  const int kB = tid >> 4, nB = (tid & 15) * 4;
  const int rid = ids[bm + mA];          // embedding row for this A row
  float acc[4][4] = {{0.f}};
  for (int k0 = 0; k0 < K; k0 += 16) {
    float4 a4 = *(const float4*)(emb + (size_t)rid*EMBD + k0 + kqA);
    As[kqA+0][mA] = a4.x; As[kqA+1][mA] = a4.y;
    As[kqA+2][mA] = a4.z; As[kqA+3][mA] = a4.w;
    *(float4*)&Bs[kB][nB] = *(const float4*)(B + (size_t)(k0 + kB)*N + bn + nB);
    __syncthreads();
    #pragma unroll
    for (int k = 0; k < 16; k++) {
      float4 av = *(float4*)&As[k][ty*4];
      float4 bv = *(float4*)&Bs[k][tx*4];
      float ar[4] = {av.x, av.y, av.z, av.w};
      float br[4] = {bv.x, bv.y, bv.z, bv.w};
      #pragma unroll
      for (int i = 0; i < 4; i++)
        #pragma unroll
        for (int j = 0; j < 4; j++)
          acc[i][j] += ar[i] * br[j];
    }
    __syncthreads();
  }
  float4 bi = *(const float4*)(bias + bn + tx*4);
  #pragma unroll
  for (int i = 0; i < 4; i++) {
    float4 o;
    o.x = acc[i][0] + bi.x; o.y = acc[i][1] + bi.y;
    o.z = acc[i][2] + bi.z; o.w = acc[i][3] + bi.w;
    *(float4*)(C + (size_t)(bm + ty*4 + i)*N + bn + tx*4) = o;
  }
}

// ---------------- f32 tiled GEMM: C = A@B + bias (64x64) ----------------
__global__ __launch_bounds__(256) void gemm_nn_bias(
    const float* __restrict__ A, const float* __restrict__ B,
    const float* __restrict__ bias, float* __restrict__ C,
    int M, int N, int K) {
  __shared__ float As[16][64];
  __shared__ float Bs[16][64];
  const int tid = threadIdx.x;
  const int bm = blockIdx.y * 64;
  const int bn = blockIdx.x * 64;
  const int tx = tid & 15, ty = tid >> 4;
  const int mA = tid >> 2, kqA = (tid & 3) * 4;
  const int kB = tid >> 4, nB = (tid & 15) * 4;
  float acc[4][4] = {{0.f}};
  for (int k0 = 0; k0 < K; k0 += 16) {
    float4 a4 = *(const float4*)(A + (size_t)(bm + mA)*K + k0 + kqA);
    As[kqA+0][mA] = a4.x; As[kqA+1][mA] = a4.y;
    As[kqA+2][mA] = a4.z; As[kqA+3][mA] = a4.w;
    *(float4*)&Bs[kB][nB] = *(const float4*)(B + (size_t)(k0 + kB)*N + bn + nB);
    __syncthreads();
    #pragma unroll
    for (int k = 0; k < 16; k++) {
      float4 av = *(float4*)&As[k][ty*4];
      float4 bv = *(float4*)&Bs[k][tx*4];
      float ar[4] = {av.x, av.y, av.z, av.w};
      float br[4] = {bv.x, bv.y, bv.z, bv.w};
      #pragma unroll
      for (int i = 0; i < 4; i++)
        #pragma unroll
        for (int j = 0; j < 4; j++)
          acc[i][j] += ar[i] * br[j];
    }
    __syncthreads();
  }
  float4 bi = *(const float4*)(bias + bn + tx*4);
  #pragma unroll
  for (int i = 0; i < 4; i++) {
    float4 o;
    o.x = acc[i][0] + bi.x; o.y = acc[i][1] + bi.y;
    o.z = acc[i][2] + bi.z; o.w = acc[i][3] + bi.w;
    *(float4*)(C + (size_t)(bm + ty*4 + i)*N + bn + tx*4) = o;
  }
}

// ------- logits GEMM, 128x128 tile, 8x8/thread: C = A @ Bt^T with pad-mask --
__global__ __launch_bounds__(256) void gemm_nt_logits128(
    const float* __restrict__ A,   // P [2048, 512] (in d_ws — not aliasing C)
    const float* __restrict__ Bt,  // emb [32000, 512]
    const int* __restrict__ ids,   // [2048]
    float* __restrict__ C) {       // [2048, 32000]
  const int K = EMBD, N = VOCAB;
  __shared__ float As[16][128];
  __shared__ float Bs[16][128];
  const int tid = threadIdx.x;
  const int bm = blockIdx.y * 128;
  const int bn = blockIdx.x * 128;
  const int tx = tid & 15, ty = tid >> 4;
  const int rL = tid >> 1, kL = (tid & 1) * 8;   // loader: row 0..127, k 0/8
  float acc[8][8] = {{0.f}};
  for (int k0 = 0; k0 < K; k0 += 16) {
    float4 a0 = *(const float4*)(A  + (size_t)(bm + rL)*K + k0 + kL);
    float4 a1 = *(const float4*)(A  + (size_t)(bm + rL)*K + k0 + kL + 4);
    float4 b0 = *(const float4*)(Bt + (size_t)(bn + rL)*K + k0 + kL);
    float4 b1 = *(const float4*)(Bt + (size_t)(bn + rL)*K + k0 + kL + 4);
    __syncthreads();   // previous iteration's LDS reads complete
    As[kL+0][rL] = a0.x; As[kL+1][rL] = a0.y; As[kL+2][rL] = a0.z; As[kL+3][rL] = a0.w;
    As[kL+4][rL] = a1.x; As[kL+5][rL] = a1.y; As[kL+6][rL] = a1.z; As[kL+7][rL] = a1.w;
    Bs[kL+0][rL] = b0.x; Bs[kL+1][rL] = b0.y; Bs[kL+2][rL] = b0.z; Bs[kL+3][rL] = b0.w;
    Bs[kL+4][rL] = b1.x; Bs[kL+5][rL] = b1.y; Bs[kL+6][rL] = b1.z; Bs[kL+7][rL] = b1.w;
    __syncthreads();
    #pragma unroll
    for (int k = 0; k < 16; k++) {
      float4 av0 = *(float4*)&As[k][ty*4];
      float4 av1 = *(float4*)&As[k][64 + ty*4];
      float4 bv0 = *(float4*)&Bs[k][tx*4];
      float4 bv1 = *(float4*)&Bs[k][64 + tx*4];
      float ar[8] = {av0.x, av0.y, av0.z, av0.w, av1.x, av1.y, av1.z, av1.w};
      float br[8] = {bv0.x, bv0.y, bv0.z, bv0.w, bv1.x, bv1.y, bv1.z, bv1.w};
      #pragma unroll
      for (int i = 0; i < 8; i++)
        #pragma unroll
        for (int j = 0; j < 8; j++)
          acc[i][j] += ar[i] * br[j];
    }
  }
  #pragma unroll
  for (int i = 0; i < 8; i++) {
    const int row = bm + ((i < 4) ? (ty*4 + i) : (64 + ty*4 + i - 4));
    const bool mk = ids[row] != 0;
    float4 o0, o1;
    if (mk) {
      o0 = make_float4(acc[i][0], acc[i][1], acc[i][2], acc[i][3]);
      o1 = make_float4(acc[i][4], acc[i][5], acc[i][6], acc[i][7]);
    } else {
      o0 = make_float4((bn + tx*4 == 0) ? 1.f : 0.f, 0.f, 0.f, 0.f);
      o1 = make_float4(0.f, 0.f, 0.f, 0.f);
    }
    *(float4*)(C + (size_t)row*N + bn + tx*4)      = o0;
    *(float4*)(C + (size_t)row*N + bn + 64 + tx*4) = o1;
  }
}

// ---------------- fused 2-layer pipelined LSTM recurrence -------------------
// Round-14 structure, exchange converted to TAGGED data-as-signal:
// every published h-value is a u64 (tag<<32 | f32-bits) stored with one
// relaxed device-scope atomic (single-copy atomic => tag+value arrive
// together). Consumers issue their dedup gather immediately and re-load only
// stale entries — no flags, no vmcnt-before-flag, no poll round-trip.
//  A: H0x [SLEN][4096] u64, write-once rows; row t carries tag t+1.
//     A(t) gathers row t-1 wanting tag t (monotone; A never waits on B).
//  B: h0 from H0x row t (tag t+1); h1 via Hx1t [2][4096] u64 2-slot:
//     B end of step t writes slot (t+1)&1 with tag t+1; B(t) reads slot t&1
//     wanting tag t. Slot overwrite at step t+1 requires all blocks' step-t
//     publishes, which follow their phase-2 reads -> no overwrite hazard;
//     per-entry tag check is the backstop. Replay-safe: stale tags from a
//     previous replay carry identical (deterministic) values; zero/poison
//     tags never match wanted t>=1.
__device__ __forceinline__ int rev5(int l) {
  return ((l & 1) << 4) | ((l & 2) << 2) | (l & 4) | ((l & 8) >> 2) | ((l & 16) >> 4);
}

#define HALVE(MASK, SH, HSZ)                          \
    { const int bit_ = (lane >> SH) & 1;              \
      _Pragma("unroll")                               \
      for (int j = 0; j < HSZ; j++) {                 \
        float snd = bit_ ? a[j] : a[j + HSZ];         \
        float kep = bit_ ? a[j + HSZ] : a[j];         \
        a[j] = kep + __shfl_xor(snd, MASK);           \
      } }

// dedup tagged gather: 16 u64/thread from src[tid + r*256], spin until every
// entry's high word == want, then deposit the f32 payloads into hs.
#define TAG_GATHER(SRC, WANT)                                   \
    { u64 v_[16];                                               \
      _Pragma("unroll")                                         \
      for (int r = 0; r < 16; r++)                              \
        v_[r] = AL((SRC) + tid + (r << 8));                     \
      while (true) {                                            \
        unsigned stale_ = 0;                                    \
        _Pragma("unroll")                                       \
        for (int r = 0; r < 16; r++)                            \
          stale_ |= ((unsigned)(v_[r] >> 32) != (WANT)) ? (1u << r) : 0u; \
        if (stale_ == 0) break;                                 \
        __builtin_amdgcn_s_sleep(1);                            \
        _Pragma("unroll")                                       \
        for (int r = 0; r < 16; r++)                            \
          if (stale_ & (1u << r))                               \
            v_[r] = AL((SRC) + tid + (r << 8));                 \
      }                                                         \
      _Pragma("unroll")                                         \
      for (int r = 0; r < 16; r++)                              \
        hs[tid + (r << 8)] = __uint_as_float((unsigned)v_[r]);  }

__global__ __launch_bounds__(256, 1) void lstm_fused(
    const float* __restrict__ Z0,     // [B*S, 4096] x@Wk0 + b0
    const float* __restrict__ Wr0T,   // [4096][1024]
    const float* __restrict__ Wk1T,   // [4096][1024]
    const float* __restrict__ Wr1T,   // [4096][1024]
    const float* __restrict__ bias1,  // [4096]
    const int* __restrict__ ids,      // [B*S]
    float* __restrict__ H1,           // [B*S, 1024] layer-1 h sequence
    u64* __restrict__ H0x,            // [SLEN][4096] tagged h0 (write-once)
    u64* __restrict__ Hx1t) {         // [2][4096] tagged h1 (2-slot)
  __shared__ float wk[32][1024];      // B only: Wk1 cols (128 KB)
  __shared__ float hs[NBAT * HIDD];   // staged h vector (16 KB, reused)
  __shared__ float z_s[4][64];
  __shared__ float zc[128];
  const int tid  = threadIdx.x;
  const int lane = tid & 63;
  const int w    = tid >> 6;
  const int ccH  = tid >> 7;          // 0..1 (which 16 of the 32 gate cols)
  const int part = tid & 127;         // k-slice owner (8 k values per matrix)

  if (blockIdx.x < ABLK) {
    // ================= role A: layer-0, 8 units =================
    const int hbase = blockIdx.x * 8;
    float4 Wf[16], Wg[16];
    #pragma unroll
    for (int cl = 0; cl < 16; cl++) {
      const int cc = ccH * 16 + cl;
      const int g  = cc >> 3, d = cc & 7;
      const size_t col = (size_t)(g * HIDD + hbase + d);
      Wf[cl] = *(const float4*)(Wr0T + col * HIDD + 4 * part);
      Wg[cl] = *(const float4*)(Wr0T + col * HIDD + 512 + 4 * part);
    }
    float c_reg = 0.f, h_reg = 0.f;
    __syncthreads();

    for (int t = 0; t < SLEN; t++) {
      float pz0 = 0.f, pz1 = 0.f, pz2 = 0.f, pz3 = 0.f;
      int pmk = 0;
      if (tid < 32) {
        const int b = tid >> 3, d = tid & 7;
        const float* zrow = Z0 + (size_t)(b*SLEN + t) * GATE4 + hbase + d;
        pz0 = zrow[0];      pz1 = zrow[HIDD];
        pz2 = zrow[2*HIDD]; pz3 = zrow[3*HIDD];
        pmk = ids[b*SLEN + t];
      }
      float4 ha[NBAT], hb[NBAT];
      if (t > 0) {
        // tagged dedup gather of h0(t-1): row t-1 carries tag t
        const u64* src = H0x + (size_t)(t - 1) * 4096;
        TAG_GATHER(src, (unsigned)t);
        __syncthreads();
        #pragma unroll
        for (int b = 0; b < NBAT; b++) {
          ha[b] = *(const float4*)(hs + b*HIDD + 4*part);
          hb[b] = *(const float4*)(hs + b*HIDD + 512 + 4*part);
        }
      } else {
        #pragma unroll
        for (int b = 0; b < NBAT; b++) {
          ha[b] = make_float4(0.f, 0.f, 0.f, 0.f);
          hb[b] = make_float4(0.f, 0.f, 0.f, 0.f);
        }
      }
      float a[64];
      #pragma unroll
      for (int cl = 0; cl < 16; cl++)
        #pragma unroll
        for (int b = 0; b < NBAT; b++)
          a[cl*4 + b] = Wf[cl].x*ha[b].x + Wf[cl].y*ha[b].y
                      + Wf[cl].z*ha[b].z + Wf[cl].w*ha[b].w
                      + Wg[cl].x*hb[b].x + Wg[cl].y*hb[b].y
                      + Wg[cl].z*hb[b].z + Wg[cl].w*hb[b].w;
      #pragma unroll
      for (int i = 0; i < 64; i++) a[i] += __shfl_xor(a[i], 32);
      HALVE(1, 0, 32) HALVE(2, 1, 16) HALVE(4, 2, 8) HALVE(8, 3, 4) HALVE(16, 4, 2)
      if (lane < 32) {
        z_s[w][rev5(lane)*2 + 0] = a[0];
        z_s[w][rev5(lane)*2 + 1] = a[1];
      }
      __syncthreads();
      if (tid < 128) {
        const int cc = tid >> 2, b = tid & 3;
        const int cH = cc >> 4, i = ((cc & 15) << 2) | b;
        zc[tid] = z_s[2*cH][i] + z_s[2*cH + 1][i];
      }
      __syncthreads();
      if (tid < 32) {
        const int b = tid >> 3, d = tid & 7;
        const float zi = zc[((0*8 + d) << 2) + b] + pz0;
        const float zf = zc[((1*8 + d) << 2) + b] + pz1;
        const float zg = zc[((2*8 + d) << 2) + b] + pz2;
        const float zo = zc[((3*8 + d) << 2) + b] + pz3;
        const float ig = 1.f / (1.f + expf(-zi));
        const float fg = 1.f / (1.f + expf(-zf));
        const float gg = tanhf(zg);
        const float og = 1.f / (1.f + expf(-zo));
        const float cn = fg * c_reg + ig * gg;
        const float hn = og * tanhf(cn);
        const bool mk = pmk != 0;
        const float ho = mk ? hn : h_reg;
        c_reg = mk ? cn : c_reg;
        h_reg = ho;
        // publish tagged: row t carries tag t+1 (data IS the signal)
        AS(H0x + (size_t)t * 4096 + b*HIDD + hbase + d,
           ((u64)(unsigned)(t + 1) << 32) | (u64)__float_as_uint(ho));
      }
      __syncthreads();  // hs/z_s/zc reuse safety
    }
  } else {
    // ================= role B: layer-1, 8 units =================
    const int bid = blockIdx.x - ABLK;   // 0..127
    const int ub  = bid * 8;
    // stage this block's 32 Wk1 columns into LDS (128 KB), coalesced
    for (int i = tid; i < 32 * 256; i += 256) {
      const int c2 = i >> 8, k4 = i & 255;
      const size_t col = (size_t)((c2 >> 3) * HIDD + ub + (c2 & 7));
      *(float4*)&wk[c2][k4 * 4] = *(const float4*)(Wk1T + col * HIDD + 4 * k4);
    }
    float4 Rf[16], Rg[16];
    #pragma unroll
    for (int cl = 0; cl < 16; cl++) {
      const int cc = ccH * 16 + cl;
      const int g  = cc >> 3, d = cc & 7;
      const size_t col = (size_t)(g * HIDD + ub + d);
      Rf[cl] = *(const float4*)(Wr1T + col * HIDD + 4 * part);
      Rg[cl] = *(const float4*)(Wr1T + col * HIDD + 512 + 4 * part);
    }
    float pbi = 0.f, pbf = 0.f, pbg = 0.f, pbo = 0.f;
    if (tid < 32) {
      const int d = tid & 7;
      pbi = bias1[0*HIDD + ub + d];
      pbf = bias1[1*HIDD + ub + d];
      pbg = bias1[2*HIDD + ub + d];
      pbo = bias1[3*HIDD + ub + d];
    }
    float c_reg = 0.f, h_reg = 0.f;
    __syncthreads();   // wk ready

    for (int t = 0; t < SLEN; t++) {
      int pmk = 0;
      if (tid < 32) pmk = ids[(tid >> 3) * SLEN + t];
      // ---- phase 1 (off the B-chain): tagged gather h0(t), tag t+1 ----
      {
        const u64* h0p = H0x + (size_t)t * 4096;
        TAG_GATHER(h0p, (unsigned)(t + 1));
      }
      __syncthreads();
      // pass 1: z = Wk1(LDS) . h0(t)
      float4 xa[NBAT], xb[NBAT];
      #pragma unroll
      for (int b = 0; b < NBAT; b++) {
        xa[b] = *(const float4*)(hs + b*HIDD + 4*part);
        xb[b] = *(const float4*)(hs + b*HIDD + 512 + 4*part);
      }
      float a[64];
      #pragma unroll
      for (int cl = 0; cl < 16; cl++) {
        const int c2 = ccH * 16 + cl;
        const float4 kf = *(const float4*)&wk[c2][4 * part];
        const float4 kg = *(const float4*)&wk[c2][512 + 4 * part];
        #pragma unroll
        for (int b = 0; b < NBAT; b++) {
          a[cl*4 + b] = kf.x*xa[b].x + kf.y*xa[b].y + kf.z*xa[b].z + kf.w*xa[b].w
                      + kg.x*xb[b].x + kg.y*xb[b].y + kg.z*xb[b].z + kg.w*xb[b].w;
        }
      }
      // ---- phase 2 (the B-chain): tagged gather h1(t-1), slot t&1, tag t --
      if (t > 0) {
        __syncthreads();   // all pass-1 hs reads complete before overwrite
        {
          const u64* h1p = Hx1t + (size_t)(t & 1) * 4096;
          TAG_GATHER(h1p, (unsigned)t);
        }
        __syncthreads();
        float4 ya[NBAT], yb[NBAT];
        #pragma unroll
        for (int b = 0; b < NBAT; b++) {
          ya[b] = *(const float4*)(hs + b*HIDD + 4*part);
          yb[b] = *(const float4*)(hs + b*HIDD + 512 + 4*part);
        }
        // pass 2: z += Wr1(regs) . h1(t-1)
        #pragma unroll
        for (int cl = 0; cl < 16; cl++) {
          #pragma unroll
          for (int b = 0; b < NBAT; b++) {
            a[cl*4 + b] += Rf[cl].x*ya[b].x + Rf[cl].y*ya[b].y
                         + Rf[cl].z*ya[b].z + Rf[cl].w*ya[b].w
                         + Rg[cl].x*yb[b].x + Rg[cl].y*yb[b].y
                         + Rg[cl].z*yb[b].z + Rg[cl].w*yb[b].w;
          }
        }
      }
      #pragma unroll
      for (int i = 0; i < 64; i++) a[i] += __shfl_xor(a[i], 32);
      HALVE(1, 0, 32) HALVE(2, 1, 16) HALVE(4, 2, 8) HALVE(8, 3, 4) HALVE(16, 4, 2)
      if (lane < 32) {
        z_s[w][rev5(lane)*2 + 0] = a[0];
        z_s[w][rev5(lane)*2 + 1] = a[1];
      }
      __syncthreads();
      if (tid < 128) {
        const int cc = tid >> 2, b = tid & 3;
        const int cH = cc >> 4, i = ((cc & 15) << 2) | b;
        zc[tid] = z_s[2*cH][i] + z_s[2*cH + 1][i];
      }
      __syncthreads();
      if (tid < 32) {
        const int b = tid >> 3, d = tid & 7;
        const float zi = zc[((0*8 + d) << 2) + b] + pbi;
        const float zf = zc[((1*8 + d) << 2) + b] + pbf;
        const float zg = zc[((2*8 + d) << 2) + b] + pbg;
        const float zo = zc[((3*8 + d) << 2) + b] + pbo;
        const float ig = 1.f / (1.f + expf(-zi));
        const float fg = 1.f / (1.f + expf(-zf));
        const float gg = tanhf(zg);
        const float og = 1.f / (1.f + expf(-zo));
        const float cn = fg * c_reg + ig * gg;
        const float hn = og * tanhf(cn);
        const bool mk = pmk != 0;
        const float ho = mk ? hn : h_reg;
        c_reg = mk ? cn : c_reg;
        h_reg = ho;
        H1[(size_t)(b*SLEN + t) * HIDD + ub + d] = ho;   // plain (kernel-final)
        // publish tagged h1(t): slot (t+1)&1 carries tag t+1
        AS(Hx1t + (size_t)((t + 1) & 1) * 4096 + b*HIDD + ub + d,
           ((u64)(unsigned)(t + 1) << 32) | (u64)__float_as_uint(ho));
      }
      __syncthreads();  // hs/z_s/zc reuse safety
    }
  }
}
#undef TAG_GATHER
#undef HALVE

extern "C" void kernel_launch(void* const* d_in, const int* in_sizes, int n_in,
                              void* d_out, int out_size, void* d_ws, size_t ws_size,
                              hipStream_t stream) {
  const int*   ids = (const int*)  d_in[0];
  const float* emb = (const float*)d_in[1];
  const float* Wk0 = (const float*)d_in[2];
  const float* Wr0 = (const float*)d_in[3];
  const float* b0  = (const float*)d_in[4];
  const float* Wk1 = (const float*)d_in[5];
  const float* Wr1 = (const float*)d_in[6];
  const float* b1  = (const float*)d_in[7];
  const float* Wp  = (const float*)d_in[8];
  const float* bp  = (const float*)d_in[9];
  float* out = (float*)d_out;

  // DEAD-before-logits intermediates in the head of d_out; cross-kernel live
  // data (Hx1t, P) in d_ws.
  float* Z      = out;                  // [2048, 4096]  8,388,608 f (L0)
  float* H1     = out + 8388608;        // [2048, 1024]  2,097,152 f
  float* Wr0T   = out + 10485760;       // [4096][1024]  4,194,304 f
  float* Wr1T   = out + 14680064;       // [4096][1024]  4,194,304 f
  float* Wk1T   = out + 18874368;       // [4096][1024]  4,194,304 f
  u64*   H0x    = (u64*)(out + 23068672);  // [512][4096] u64 = 16 MB
  u64*   Hx1t   = (u64*)d_ws;           // [2][4096] u64 = 64 KB
  float* P      = ((float*)d_ws) + 16384;  // [2048, 512] = 4 MB

  // zero Hx1t once per launch: tag 0 never matches wanted tags >=1
  hipMemsetAsync(Hx1t, 0, 2 * 4096 * sizeof(u64), stream);
  transpose_k<<<dim3(128, 32), 256, 0, stream>>>(Wr0, Wr0T);
  transpose_k<<<dim3(128, 32), 256, 0, stream>>>(Wr1, Wr1T);
  transpose_k<<<dim3(128, 32), 256, 0, stream>>>(Wk1, Wk1T);
  gemm_nn_emb<<<dim3(64, 32), 256, 0, stream>>>(ids, emb, Wk0, b0, Z, 4096, 512);
  lstm_fused<<<ABLK + BBLK, 256, 0, stream>>>(Z, Wr0T, Wk1T, Wr1T, b1, ids,
                                              H1, H0x, Hx1t);
  gemm_nn_bias<<<dim3(8, 32), 256, 0, stream>>>(H1, Wp, bp, P, 2048, 512, 1024);
  gemm_nt_logits128<<<dim3(250, 16), 256, 0, stream>>>(P, emb, ids, out);
}

// Round 16
// 4187.366 us; speedup vs baseline: 1.0181x; 1.0181x over previous
//
#include <hip/hip_runtime.h>

#define VOCAB 32000
#define EMBD  512
#define HIDD  1024
#define SLEN  512
#define NBAT  4
#define GATE4 4096   // 4*HIDD
#define ABLK  128    // layer-0 blocks, 8 units each
#define BBLK  128    // layer-1 blocks, 8 units each (Wk1 in LDS, Wr1 in regs)

typedef unsigned long long u64;

#define AL(p) __hip_atomic_load((p), __ATOMIC_RELAXED, __HIP_MEMORY_SCOPE_AGENT)
#define AS(p, v) __hip_atomic_store((p), (v), __ATOMIC_RELAXED, __HIP_MEMORY_SCOPE_AGENT)

// ---------------- 32x32 tiled transpose: [1024][4096] -> [4096][1024] -------
__global__ __launch_bounds__(256) void transpose_k(const float* __restrict__ src,
                                                   float* __restrict__ dst) {
  __shared__ float t[32][33];
  const int bx = blockIdx.x * 32;
  const int by = blockIdx.y * 32;
  const int r0 = threadIdx.x >> 5;
  const int c  = threadIdx.x & 31;
  #pragma unroll
  for (int i = 0; i < 4; i++) {
    const int r = r0 + i*8;
    t[r][c] = src[(size_t)(by + r)*GATE4 + bx + c];
  }
  __syncthreads();
  #pragma unroll
  for (int i = 0; i < 4; i++) {
    const int rw = r0 + i*8;
    dst[(size_t)(bx + rw)*HIDD + by + c] = t[c][rw];
  }
}

// -------- layer-0 input GEMM with fused embedding gather, 128x128 tile:
// Z[m][n] = sum_k emb[ids[m]][k] * Wk0[k][n] + b0[n]   (M=2048,N=4096,K=512)
__global__ __launch_bounds__(256) void gemm_nn_emb128(
    const int* __restrict__ ids, const float* __restrict__ emb,
    const float* __restrict__ B, const float* __restrict__ bias,
    float* __restrict__ C) {
  const int N = GATE4, K = EMBD;
  __shared__ float As[16][128];
  __shared__ float Bs[16][128];
  const int tid = threadIdx.x;
  const int bm = blockIdx.y * 128;
  const int bn = blockIdx.x * 128;
  const int tx = tid & 15, ty = tid >> 4;
  const int rL = tid >> 1, kL = (tid & 1) * 8;   // A loader: row, k-offset
  const int kB = tid >> 4, nB = (tid & 15) * 8;  // B loader: k-row, col
  const int rid = ids[bm + rL];
  float acc[8][8] = {{0.f}};
  for (int k0 = 0; k0 < K; k0 += 16) {
    float4 a0 = *(const float4*)(emb + (size_t)rid*EMBD + k0 + kL);
    float4 a1 = *(const float4*)(emb + (size_t)rid*EMBD + k0 + kL + 4);
    float4 b0 = *(const float4*)(B + (size_t)(k0 + kB)*N + bn + nB);
    float4 b1 = *(const float4*)(B + (size_t)(k0 + kB)*N + bn + nB + 4);
    __syncthreads();   // previous iteration's LDS reads complete
    As[kL+0][rL] = a0.x; As[kL+1][rL] = a0.y; As[kL+2][rL] = a0.z; As[kL+3][rL] = a0.w;
    As[kL+4][rL] = a1.x; As[kL+5][rL] = a1.y; As[kL+6][rL] = a1.z; As[kL+7][rL] = a1.w;
    *(float4*)&Bs[kB][nB]     = b0;
    *(float4*)&Bs[kB][nB + 4] = b1;
    __syncthreads();
    #pragma unroll
    for (int k = 0; k < 16; k++) {
      float4 av0 = *(float4*)&As[k][ty*4];
      float4 av1 = *(float4*)&As[k][64 + ty*4];
      float4 bv0 = *(float4*)&Bs[k][tx*4];
      float4 bv1 = *(float4*)&Bs[k][64 + tx*4];
      float ar[8] = {av0.x, av0.y, av0.z, av0.w, av1.x, av1.y, av1.z, av1.w};
      float br[8] = {bv0.x, bv0.y, bv0.z, bv0.w, bv1.x, bv1.y, bv1.z, bv1.w};
      #pragma unroll
      for (int i = 0; i < 8; i++)
        #pragma unroll
        for (int j = 0; j < 8; j++)
          acc[i][j] += ar[i] * br[j];
    }
  }
  float4 bi0 = *(const float4*)(bias + bn + tx*4);
  float4 bi1 = *(const float4*)(bias + bn + 64 + tx*4);
  #pragma unroll
  for (int i = 0; i < 8; i++) {
    const int row = bm + ((i < 4) ? (ty*4 + i) : (64 + ty*4 + i - 4));
    float4 o0 = make_float4(acc[i][0] + bi0.x, acc[i][1] + bi0.y,
                            acc[i][2] + bi0.z, acc[i][3] + bi0.w);
    float4 o1 = make_float4(acc[i][4] + bi1.x, acc[i][5] + bi1.y,
                            acc[i][6] + bi1.z, acc[i][7] + bi1.w);
    *(float4*)(C + (size_t)row*N + bn + tx*4)      = o0;
    *(float4*)(C + (size_t)row*N + bn + 64 + tx*4) = o1;
  }
}

// ---------------- f32 tiled GEMM: C = A@B + bias (64x64) ----------------
__global__ __launch_bounds__(256) void gemm_nn_bias(
    const float* __restrict__ A, const float* __restrict__ B,
    const float* __restrict__ bias, float* __restrict__ C,
    int M, int N, int K) {
  __shared__ float As[16][64];
  __shared__ float Bs[16][64];
  const int tid = threadIdx.x;
  const int bm = blockIdx.y * 64;
  const int bn = blockIdx.x * 64;
  const int tx = tid & 15, ty = tid >> 4;
  const int mA = tid >> 2, kqA = (tid & 3) * 4;
  const int kB = tid >> 4, nB = (tid & 15) * 4;
  float acc[4][4] = {{0.f}};
  for (int k0 = 0; k0 < K; k0 += 16) {
    float4 a4 = *(const float4*)(A + (size_t)(bm + mA)*K + k0 + kqA);
    As[kqA+0][mA] = a4.x; As[kqA+1][mA] = a4.y;
    As[kqA+2][mA] = a4.z; As[kqA+3][mA] = a4.w;
    *(float4*)&Bs[kB][nB] = *(const float4*)(B + (size_t)(k0 + kB)*N + bn + nB);
    __syncthreads();
    #pragma unroll
    for (int k = 0; k < 16; k++) {
      float4 av = *(float4*)&As[k][ty*4];
      float4 bv = *(float4*)&Bs[k][tx*4];
      float ar[4] = {av.x, av.y, av.z, av.w};
      float br[4] = {bv.x, bv.y, bv.z, bv.w};
      #pragma unroll
      for (int i = 0; i < 4; i++)
        #pragma unroll
        for (int j = 0; j < 4; j++)
          acc[i][j] += ar[i] * br[j];
    }
    __syncthreads();
  }
  float4 bi = *(const float4*)(bias + bn + tx*4);
  #pragma unroll
  for (int i = 0; i < 4; i++) {
    float4 o;
    o.x = acc[i][0] + bi.x; o.y = acc[i][1] + bi.y;
    o.z = acc[i][2] + bi.z; o.w = acc[i][3] + bi.w;
    *(float4*)(C + (size_t)(bm + ty*4 + i)*N + bn + tx*4) = o;
  }
}

// ------- logits GEMM, 128x128 tile, 8x8/thread: C = A @ Bt^T with pad-mask --
__global__ __launch_bounds__(256) void gemm_nt_logits128(
    const float* __restrict__ A,   // P [2048, 512] (in d_ws — not aliasing C)
    const float* __restrict__ Bt,  // emb [32000, 512]
    const int* __restrict__ ids,   // [2048]
    float* __restrict__ C) {       // [2048, 32000]
  const int K = EMBD, N = VOCAB;
  __shared__ float As[16][128];
  __shared__ float Bs[16][128];
  const int tid = threadIdx.x;
  const int bm = blockIdx.y * 128;
  const int bn = blockIdx.x * 128;
  const int tx = tid & 15, ty = tid >> 4;
  const int rL = tid >> 1, kL = (tid & 1) * 8;   // loader: row 0..127, k 0/8
  float acc[8][8] = {{0.f}};
  for (int k0 = 0; k0 < K; k0 += 16) {
    float4 a0 = *(const float4*)(A  + (size_t)(bm + rL)*K + k0 + kL);
    float4 a1 = *(const float4*)(A  + (size_t)(bm + rL)*K + k0 + kL + 4);
    float4 b0 = *(const float4*)(Bt + (size_t)(bn + rL)*K + k0 + kL);
    float4 b1 = *(const float4*)(Bt + (size_t)(bn + rL)*K + k0 + kL + 4);
    __syncthreads();   // previous iteration's LDS reads complete
    As[kL+0][rL] = a0.x; As[kL+1][rL] = a0.y; As[kL+2][rL] = a0.z; As[kL+3][rL] = a0.w;
    As[kL+4][rL] = a1.x; As[kL+5][rL] = a1.y; As[kL+6][rL] = a1.z; As[kL+7][rL] = a1.w;
    Bs[kL+0][rL] = b0.x; Bs[kL+1][rL] = b0.y; Bs[kL+2][rL] = b0.z; Bs[kL+3][rL] = b0.w;
    Bs[kL+4][rL] = b1.x; Bs[kL+5][rL] = b1.y; Bs[kL+6][rL] = b1.z; Bs[kL+7][rL] = b1.w;
    __syncthreads();
    #pragma unroll
    for (int k = 0; k < 16; k++) {
      float4 av0 = *(float4*)&As[k][ty*4];
      float4 av1 = *(float4*)&As[k][64 + ty*4];
      float4 bv0 = *(float4*)&Bs[k][tx*4];
      float4 bv1 = *(float4*)&Bs[k][64 + tx*4];
      float ar[8] = {av0.x, av0.y, av0.z, av0.w, av1.x, av1.y, av1.z, av1.w};
      float br[8] = {bv0.x, bv0.y, bv0.z, bv0.w, bv1.x, bv1.y, bv1.z, bv1.w};
      #pragma unroll
      for (int i = 0; i < 8; i++)
        #pragma unroll
        for (int j = 0; j < 8; j++)
          acc[i][j] += ar[i] * br[j];
    }
  }
  #pragma unroll
  for (int i = 0; i < 8; i++) {
    const int row = bm + ((i < 4) ? (ty*4 + i) : (64 + ty*4 + i - 4));
    const bool mk = ids[row] != 0;
    float4 o0, o1;
    if (mk) {
      o0 = make_float4(acc[i][0], acc[i][1], acc[i][2], acc[i][3]);
      o1 = make_float4(acc[i][4], acc[i][5], acc[i][6], acc[i][7]);
    } else {
      o0 = make_float4((bn + tx*4 == 0) ? 1.f : 0.f, 0.f, 0.f, 0.f);
      o1 = make_float4(0.f, 0.f, 0.f, 0.f);
    }
    *(float4*)(C + (size_t)row*N + bn + tx*4)      = o0;
    *(float4*)(C + (size_t)row*N + bn + 64 + tx*4) = o1;
  }
}

// ---------------- fused 2-layer pipelined LSTM recurrence -------------------
// EXACT round-14 kernel (best measured: 3.35 ms, hop 6.5us, VGPR 256, zero
// spill). Dedup LDS-staged gathers + B critical-path split. Round-15 showed
// tagged data-as-signal is neutral-to-worse (detection already hidden under
// phase-1 compute; MALL same-line fan-out is the floor).
__device__ __forceinline__ int rev5(int l) {
  return ((l & 1) << 4) | ((l & 2) << 2) | (l & 4) | ((l & 8) >> 2) | ((l & 16) >> 4);
}

#define HALVE(MASK, SH, HSZ)                          \
    { const int bit_ = (lane >> SH) & 1;              \
      _Pragma("unroll")                               \
      for (int j = 0; j < HSZ; j++) {                 \
        float snd = bit_ ? a[j] : a[j + HSZ];         \
        float kep = bit_ ? a[j + HSZ] : a[j];         \
        a[j] = kep + __shfl_xor(snd, MASK);           \
      } }

__global__ __launch_bounds__(256, 1) void lstm_fused(
    const float* __restrict__ Z0,     // [B*S, 4096] x@Wk0 + b0
    const float* __restrict__ Wr0T,   // [4096][1024]
    const float* __restrict__ Wk1T,   // [4096][1024]
    const float* __restrict__ Wr1T,   // [4096][1024]
    const float* __restrict__ bias1,  // [4096]
    const int* __restrict__ ids,      // [B*S]
    float* __restrict__ H1,           // [B*S, 1024] layer-1 h sequence
    float* __restrict__ H0full,       // [SLEN][4][1024] streamed h0
    unsigned* __restrict__ flgA,      // [128*16] (zeroed)
    unsigned* __restrict__ flgB) {    // [128*16] (zeroed)
  __shared__ float wk[32][1024];      // B only: Wk1 cols (128 KB)
  __shared__ float hs[NBAT * HIDD];   // staged h vector (16 KB, reused)
  __shared__ float z_s[4][64];
  __shared__ float zc[128];
  const int tid  = threadIdx.x;
  const int lane = tid & 63;
  const int w    = tid >> 6;
  const int ccH  = tid >> 7;          // 0..1 (which 16 of the 32 gate cols)
  const int part = tid & 127;         // k-slice owner (8 k values per matrix)

  if (blockIdx.x < ABLK) {
    // ================= role A: layer-0, 8 units =================
    const int hbase = blockIdx.x * 8;
    float4 Wf[16], Wg[16];
    #pragma unroll
    for (int cl = 0; cl < 16; cl++) {
      const int cc = ccH * 16 + cl;
      const int g  = cc >> 3, d = cc & 7;
      const size_t col = (size_t)(g * HIDD + hbase + d);
      Wf[cl] = *(const float4*)(Wr0T + col * HIDD + 4 * part);
      Wg[cl] = *(const float4*)(Wr0T + col * HIDD + 512 + 4 * part);
    }
    float c_reg = 0.f, h_reg = 0.f;
    __syncthreads();

    for (int t = 0; t < SLEN; t++) {
      float pz0 = 0.f, pz1 = 0.f, pz2 = 0.f, pz3 = 0.f;
      int pmk = 0;
      if (tid < 32) {
        const int b = tid >> 3, d = tid & 7;
        const float* zrow = Z0 + (size_t)(b*SLEN + t) * GATE4 + hbase + d;
        pz0 = zrow[0];      pz1 = zrow[HIDD];
        pz2 = zrow[2*HIDD]; pz3 = zrow[3*HIDD];
        pmk = ids[b*SLEN + t];
      }
      float4 ha[NBAT], hb[NBAT];
      if (t > 0) {
        if (tid < ABLK) {
          while (AL(flgA + tid * 16) < (unsigned)t)
            __builtin_amdgcn_s_sleep(1);
        }
        __syncthreads();
        // dedup staged gather: 8 u64/thread, each address loaded once
        const u64* src = (const u64*)H0full + (size_t)(t - 1) * 2048;
        u64 v[8];
        #pragma unroll
        for (int r = 0; r < 8; r++)
          v[r] = AL(src + tid + (r << 8));
        #pragma unroll
        for (int r = 0; r < 8; r++)
          ((u64*)hs)[tid + (r << 8)] = v[r];
        __syncthreads();
        #pragma unroll
        for (int b = 0; b < NBAT; b++) {
          ha[b] = *(const float4*)(hs + b*HIDD + 4*part);
          hb[b] = *(const float4*)(hs + b*HIDD + 512 + 4*part);
        }
      } else {
        #pragma unroll
        for (int b = 0; b < NBAT; b++) {
          ha[b] = make_float4(0.f, 0.f, 0.f, 0.f);
          hb[b] = make_float4(0.f, 0.f, 0.f, 0.f);
        }
      }
      float a[64];
      #pragma unroll
      for (int cl = 0; cl < 16; cl++)
        #pragma unroll
        for (int b = 0; b < NBAT; b++)
          a[cl*4 + b] = Wf[cl].x*ha[b].x + Wf[cl].y*ha[b].y
                      + Wf[cl].z*ha[b].z + Wf[cl].w*ha[b].w
                      + Wg[cl].x*hb[b].x + Wg[cl].y*hb[b].y
                      + Wg[cl].z*hb[b].z + Wg[cl].w*hb[b].w;
      #pragma unroll
      for (int i = 0; i < 64; i++) a[i] += __shfl_xor(a[i], 32);
      HALVE(1, 0, 32) HALVE(2, 1, 16) HALVE(4, 2, 8) HALVE(8, 3, 4) HALVE(16, 4, 2)
      if (lane < 32) {
        z_s[w][rev5(lane)*2 + 0] = a[0];
        z_s[w][rev5(lane)*2 + 1] = a[1];
      }
      __syncthreads();
      if (tid < 128) {
        const int cc = tid >> 2, b = tid & 3;
        const int cH = cc >> 4, i = ((cc & 15) << 2) | b;
        zc[tid] = z_s[2*cH][i] + z_s[2*cH + 1][i];
      }
      __syncthreads();
      if (tid < 32) {
        const int b = tid >> 3, d = tid & 7;
        const float zi = zc[((0*8 + d) << 2) + b] + pz0;
        const float zf = zc[((1*8 + d) << 2) + b] + pz1;
        const float zg = zc[((2*8 + d) << 2) + b] + pz2;
        const float zo = zc[((3*8 + d) << 2) + b] + pz3;
        const float ig = 1.f / (1.f + expf(-zi));
        const float fg = 1.f / (1.f + expf(-zf));
        const float gg = tanhf(zg);
        const float og = 1.f / (1.f + expf(-zo));
        const float cn = fg * c_reg + ig * gg;
        const float hn = og * tanhf(cn);
        const bool mk = pmk != 0;
        const float ho = mk ? hn : h_reg;
        c_reg = mk ? cn : c_reg;
        h_reg = ho;
        AS(H0full + (size_t)t * (NBAT*HIDD) + b*HIDD + hbase + d, ho);
      }
      if (w == 0) {
        asm volatile("s_waitcnt vmcnt(0)" ::: "memory");
        if (tid == 0)
          AS(flgA + blockIdx.x * 16, (unsigned)(t + 1));
      }
      __syncthreads();  // hs/z_s/zc reuse safety
    }
  } else {
    // ================= role B: layer-1, 8 units =================
    const int bid = blockIdx.x - ABLK;   // 0..127
    const int ub  = bid * 8;
    // stage this block's 32 Wk1 columns into LDS (128 KB), coalesced
    for (int i = tid; i < 32 * 256; i += 256) {
      const int c2 = i >> 8, k4 = i & 255;
      const size_t col = (size_t)((c2 >> 3) * HIDD + ub + (c2 & 7));
      *(float4*)&wk[c2][k4 * 4] = *(const float4*)(Wk1T + col * HIDD + 4 * k4);
    }
    float4 Rf[16], Rg[16];
    #pragma unroll
    for (int cl = 0; cl < 16; cl++) {
      const int cc = ccH * 16 + cl;
      const int g  = cc >> 3, d = cc & 7;
      const size_t col = (size_t)(g * HIDD + ub + d);
      Rf[cl] = *(const float4*)(Wr1T + col * HIDD + 4 * part);
      Rg[cl] = *(const float4*)(Wr1T + col * HIDD + 512 + 4 * part);
    }
    float pbi = 0.f, pbf = 0.f, pbg = 0.f, pbo = 0.f;
    if (tid < 32) {
      const int d = tid & 7;
      pbi = bias1[0*HIDD + ub + d];
      pbf = bias1[1*HIDD + ub + d];
      pbg = bias1[2*HIDD + ub + d];
      pbo = bias1[3*HIDD + ub + d];
    }
    float c_reg = 0.f, h_reg = 0.f;
    __syncthreads();   // wk ready

    for (int t = 0; t < SLEN; t++) {
      int pmk = 0;
      if (tid < 32) pmk = ids[(tid >> 3) * SLEN + t];
      // ---- phase 1 (off the B-chain): h0(t) ready? A leads, so fast ----
      if (tid < 128) {
        while (AL(flgA + tid * 16) < (unsigned)(t + 1))
          __builtin_amdgcn_s_sleep(1);
      }
      __syncthreads();
      {  // dedup staged gather of h0(t)
        const u64* h0p = (const u64*)H0full + (size_t)t * 2048;
        u64 v[8];
        #pragma unroll
        for (int r = 0; r < 8; r++)
          v[r] = AL(h0p + tid + (r << 8));
        #pragma unroll
        for (int r = 0; r < 8; r++)
          ((u64*)hs)[tid + (r << 8)] = v[r];
      }
      __syncthreads();
      // pass 1: z = Wk1(LDS) . h0(t)  — before flgB poll
      float4 xa[NBAT], xb[NBAT];
      #pragma unroll
      for (int b = 0; b < NBAT; b++) {
        xa[b] = *(const float4*)(hs + b*HIDD + 4*part);
        xb[b] = *(const float4*)(hs + b*HIDD + 512 + 4*part);
      }
      float a[64];
      #pragma unroll
      for (int cl = 0; cl < 16; cl++) {
        const int c2 = ccH * 16 + cl;
        const float4 kf = *(const float4*)&wk[c2][4 * part];
        const float4 kg = *(const float4*)&wk[c2][512 + 4 * part];
        #pragma unroll
        for (int b = 0; b < NBAT; b++) {
          a[cl*4 + b] = kf.x*xa[b].x + kf.y*xa[b].y + kf.z*xa[b].z + kf.w*xa[b].w
                      + kg.x*xb[b].x + kg.y*xb[b].y + kg.z*xb[b].z + kg.w*xb[b].w;
        }
      }
      // ---- phase 2 (the B-chain): h1(t-1) ----
      if (t > 0) {
        if (tid < 128) {
          while (AL(flgB + tid * 16) < (unsigned)t)
            __builtin_amdgcn_s_sleep(1);
        }
        __syncthreads();   // also: all pass-1 hs reads complete
        {  // dedup staged gather of h1(t-1), reusing hs
          u64 v[8];
          #pragma unroll
          for (int r = 0; r < 8; r++) {
            const int idx = tid + (r << 8);
            const int b = idx >> 9, off = idx & 511;
            v[r] = AL((const u64*)H1 + (size_t)(b*SLEN + t - 1) * 512 + off);
          }
          #pragma unroll
          for (int r = 0; r < 8; r++)
            ((u64*)hs)[tid + (r << 8)] = v[r];
        }
        __syncthreads();
        float4 ya[NBAT], yb[NBAT];
        #pragma unroll
        for (int b = 0; b < NBAT; b++) {
          ya[b] = *(const float4*)(hs + b*HIDD + 4*part);
          yb[b] = *(const float4*)(hs + b*HIDD + 512 + 4*part);
        }
        // pass 2: z += Wr1(regs) . h1(t-1)
        #pragma unroll
        for (int cl = 0; cl < 16; cl++) {
          #pragma unroll
          for (int b = 0; b < NBAT; b++) {
            a[cl*4 + b] += Rf[cl].x*ya[b].x + Rf[cl].y*ya[b].y
                         + Rf[cl].z*ya[b].z + Rf[cl].w*ya[b].w
                         + Rg[cl].x*yb[b].x + Rg[cl].y*yb[b].y
                         + Rg[cl].z*yb[b].z + Rg[cl].w*yb[b].w;
          }
        }
      }
      #pragma unroll
      for (int i = 0; i < 64; i++) a[i] += __shfl_xor(a[i], 32);
      HALVE(1, 0, 32) HALVE(2, 1, 16) HALVE(4, 2, 8) HALVE(8, 3, 4) HALVE(16, 4, 2)
      if (lane < 32) {
        z_s[w][rev5(lane)*2 + 0] = a[0];
        z_s[w][rev5(lane)*2 + 1] = a[1];
      }
      __syncthreads();
      if (tid < 128) {
        const int cc = tid >> 2, b = tid & 3;
        const int cH = cc >> 4, i = ((cc & 15) << 2) | b;
        zc[tid] = z_s[2*cH][i] + z_s[2*cH + 1][i];
      }
      __syncthreads();
      if (tid < 32) {
        const int b = tid >> 3, d = tid & 7;
        const float zi = zc[((0*8 + d) << 2) + b] + pbi;
        const float zf = zc[((1*8 + d) << 2) + b] + pbf;
        const float zg = zc[((2*8 + d) << 2) + b] + pbg;
        const float zo = zc[((3*8 + d) << 2) + b] + pbo;
        const float ig = 1.f / (1.f + expf(-zi));
        const float fg = 1.f / (1.f + expf(-zf));
        const float gg = tanhf(zg);
        const float og = 1.f / (1.f + expf(-zo));
        const float cn = fg * c_reg + ig * gg;
        const float hn = og * tanhf(cn);
        const bool mk = pmk != 0;
        const float ho = mk ? hn : h_reg;
        c_reg = mk ? cn : c_reg;
        h_reg = ho;
        AS(H1 + (size_t)(b*SLEN + t) * HIDD + ub + d, ho);
      }
      if (w == 0) {
        asm volatile("s_waitcnt vmcnt(0)" ::: "memory");
        if (tid == 0)
          AS(flgB + bid * 16, (unsigned)(t + 1));
      }
      __syncthreads();  // hs/z_s/zc reuse safety
    }
  }
}
#undef HALVE

extern "C" void kernel_launch(void* const* d_in, const int* in_sizes, int n_in,
                              void* d_out, int out_size, void* d_ws, size_t ws_size,
                              hipStream_t stream) {
  const int*   ids = (const int*)  d_in[0];
  const float* emb = (const float*)d_in[1];
  const float* Wk0 = (const float*)d_in[2];
  const float* Wr0 = (const float*)d_in[3];
  const float* b0  = (const float*)d_in[4];
  const float* Wk1 = (const float*)d_in[5];
  const float* Wr1 = (const float*)d_in[6];
  const float* b1  = (const float*)d_in[7];
  const float* Wp  = (const float*)d_in[8];
  const float* bp  = (const float*)d_in[9];
  float* out = (float*)d_out;

  // DEAD-before-logits intermediates in the head of d_out; cross-kernel live
  // data (flags, P) in d_ws.
  float* Z      = out;                  // [2048, 4096]  8,388,608 f (L0)
  float* H1     = out + 8388608;        // [2048, 1024]  2,097,152 f
  float* Wr0T   = out + 10485760;       // [4096][1024]  4,194,304 f
  float* Wr1T   = out + 14680064;       // [4096][1024]  4,194,304 f
  float* Wk1T   = out + 18874368;       // [4096][1024]  4,194,304 f
  float* H0full = out + 23068672;       // [512][4096]   2,097,152 f
  unsigned* flgA = (unsigned*)d_ws;              // [128*16] u32 = 8 KB
  unsigned* flgB = (unsigned*)d_ws + 2048;       // [128*16] u32 = 8 KB
  float* P   = ((float*)d_ws) + 4096;   // [2048, 512] 1,048,576 f = 4 MB

  hipMemsetAsync(d_ws, 0, 16384, stream);  // zero both flag arrays
  transpose_k<<<dim3(128, 32), 256, 0, stream>>>(Wr0, Wr0T);
  transpose_k<<<dim3(128, 32), 256, 0, stream>>>(Wr1, Wr1T);
  transpose_k<<<dim3(128, 32), 256, 0, stream>>>(Wk1, Wk1T);
  gemm_nn_emb128<<<dim3(32, 16), 256, 0, stream>>>(ids, emb, Wk0, b0, Z);
  lstm_fused<<<ABLK + BBLK, 256, 0, stream>>>(Z, Wr0T, Wk1T, Wr1T, b1, ids,
                                              H1, H0full, flgA, flgB);
  gemm_nn_bias<<<dim3(8, 32), 256, 0, stream>>>(H1, Wp, bp, P, 2048, 512, 1024);
  gemm_nt_logits128<<<dim3(250, 16), 256, 0, stream>>>(P, emb, ids, out);
}

// Round 17
// 3877.819 us; speedup vs baseline: 1.0994x; 1.0798x over previous
//
#include <hip/hip_runtime.h>

#define VOCAB 32000
#define EMBD  512
#define HIDD  1024
#define SLEN  512
#define NBAT  4
#define GATE4 4096   // 4*HIDD
#define ABLK  128    // layer-0 blocks, 8 units each
#define BBLK  128    // layer-1 blocks, 8 units each (Wk1 in LDS, Wr1 in regs)

typedef unsigned long long u64;
typedef unsigned short ushort_t;
typedef __attribute__((ext_vector_type(8))) short bf16x8;
typedef __attribute__((ext_vector_type(4))) float f32x4;

#define AL(p) __hip_atomic_load((p), __ATOMIC_RELAXED, __HIP_MEMORY_SCOPE_AGENT)
#define AS(p, v) __hip_atomic_store((p), (v), __ATOMIC_RELAXED, __HIP_MEMORY_SCOPE_AGENT)

__device__ __forceinline__ ushort_t f2bf(float x) {   // round-to-nearest-even
  unsigned u = __float_as_uint(x);
  unsigned r = u + 0x7fffu + ((u >> 16) & 1u);
  return (ushort_t)(r >> 16);
}
__device__ __forceinline__ float bf2f(ushort_t h) {
  return __uint_as_float((unsigned)h << 16);
}

// ---------------- 32x32 tiled transpose: [1024][4096] -> [4096][1024] -------
__global__ __launch_bounds__(256) void transpose_k(const float* __restrict__ src,
                                                   float* __restrict__ dst) {
  __shared__ float t[32][33];
  const int bx = blockIdx.x * 32;
  const int by = blockIdx.y * 32;
  const int r0 = threadIdx.x >> 5;
  const int c  = threadIdx.x & 31;
  #pragma unroll
  for (int i = 0; i < 4; i++) {
    const int r = r0 + i*8;
    t[r][c] = src[(size_t)(by + r)*GATE4 + bx + c];
  }
  __syncthreads();
  #pragma unroll
  for (int i = 0; i < 4; i++) {
    const int rw = r0 + i*8;
    dst[(size_t)(bx + rw)*HIDD + by + c] = t[c][rw];
  }
}

// -------- split f32 -> (bf16 hi, bf16 lo), vectorized by float4 ----------
__global__ __launch_bounds__(256) void split_bf16_k(
    const float* __restrict__ src, ushort_t* __restrict__ hi,
    ushort_t* __restrict__ lo, int n4) {
  const int i = blockIdx.x * 256 + threadIdx.x;
  if (i >= n4) return;
  float4 v = ((const float4*)src)[i];
  ushort4 h, l;
  h.x = f2bf(v.x); l.x = f2bf(v.x - bf2f(h.x));
  h.y = f2bf(v.y); l.y = f2bf(v.y - bf2f(h.y));
  h.z = f2bf(v.z); l.z = f2bf(v.z - bf2f(h.z));
  h.w = f2bf(v.w); l.w = f2bf(v.w - bf2f(h.w));
  ((ushort4*)hi)[i] = h;
  ((ushort4*)lo)[i] = l;
}

// -------- layer-0 input GEMM with fused embedding gather, 128x128 tile ------
__global__ __launch_bounds__(256) void gemm_nn_emb128(
    const int* __restrict__ ids, const float* __restrict__ emb,
    const float* __restrict__ B, const float* __restrict__ bias,
    float* __restrict__ C) {
  const int N = GATE4, K = EMBD;
  __shared__ float As[16][128];
  __shared__ float Bs[16][128];
  const int tid = threadIdx.x;
  const int bm = blockIdx.y * 128;
  const int bn = blockIdx.x * 128;
  const int tx = tid & 15, ty = tid >> 4;
  const int rL = tid >> 1, kL = (tid & 1) * 8;
  const int kB = tid >> 4, nB = (tid & 15) * 8;
  const int rid = ids[bm + rL];
  float acc[8][8] = {{0.f}};
  for (int k0 = 0; k0 < K; k0 += 16) {
    float4 a0 = *(const float4*)(emb + (size_t)rid*EMBD + k0 + kL);
    float4 a1 = *(const float4*)(emb + (size_t)rid*EMBD + k0 + kL + 4);
    float4 b0 = *(const float4*)(B + (size_t)(k0 + kB)*N + bn + nB);
    float4 b1 = *(const float4*)(B + (size_t)(k0 + kB)*N + bn + nB + 4);
    __syncthreads();
    As[kL+0][rL] = a0.x; As[kL+1][rL] = a0.y; As[kL+2][rL] = a0.z; As[kL+3][rL] = a0.w;
    As[kL+4][rL] = a1.x; As[kL+5][rL] = a1.y; As[kL+6][rL] = a1.z; As[kL+7][rL] = a1.w;
    *(float4*)&Bs[kB][nB]     = b0;
    *(float4*)&Bs[kB][nB + 4] = b1;
    __syncthreads();
    #pragma unroll
    for (int k = 0; k < 16; k++) {
      float4 av0 = *(float4*)&As[k][ty*4];
      float4 av1 = *(float4*)&As[k][64 + ty*4];
      float4 bv0 = *(float4*)&Bs[k][tx*4];
      float4 bv1 = *(float4*)&Bs[k][64 + tx*4];
      float ar[8] = {av0.x, av0.y, av0.z, av0.w, av1.x, av1.y, av1.z, av1.w};
      float br[8] = {bv0.x, bv0.y, bv0.z, bv0.w, bv1.x, bv1.y, bv1.z, bv1.w};
      #pragma unroll
      for (int i = 0; i < 8; i++)
        #pragma unroll
        for (int j = 0; j < 8; j++)
          acc[i][j] += ar[i] * br[j];
    }
  }
  float4 bi0 = *(const float4*)(bias + bn + tx*4);
  float4 bi1 = *(const float4*)(bias + bn + 64 + tx*4);
  #pragma unroll
  for (int i = 0; i < 8; i++) {
    const int row = bm + ((i < 4) ? (ty*4 + i) : (64 + ty*4 + i - 4));
    float4 o0 = make_float4(acc[i][0] + bi0.x, acc[i][1] + bi0.y,
                            acc[i][2] + bi0.z, acc[i][3] + bi0.w);
    float4 o1 = make_float4(acc[i][4] + bi1.x, acc[i][5] + bi1.y,
                            acc[i][6] + bi1.z, acc[i][7] + bi1.w);
    *(float4*)(C + (size_t)row*N + bn + tx*4)      = o0;
    *(float4*)(C + (size_t)row*N + bn + 64 + tx*4) = o1;
  }
}

// ---------------- f32 tiled GEMM: C = A@B + bias (64x64) ----------------
__global__ __launch_bounds__(256) void gemm_nn_bias(
    const float* __restrict__ A, const float* __restrict__ B,
    const float* __restrict__ bias, float* __restrict__ C,
    int M, int N, int K) {
  __shared__ float As[16][64];
  __shared__ float Bs[16][64];
  const int tid = threadIdx.x;
  const int bm = blockIdx.y * 64;
  const int bn = blockIdx.x * 64;
  const int tx = tid & 15, ty = tid >> 4;
  const int mA = tid >> 2, kqA = (tid & 3) * 4;
  const int kB = tid >> 4, nB = (tid & 15) * 4;
  float acc[4][4] = {{0.f}};
  for (int k0 = 0; k0 < K; k0 += 16) {
    float4 a4 = *(const float4*)(A + (size_t)(bm + mA)*K + k0 + kqA);
    As[kqA+0][mA] = a4.x; As[kqA+1][mA] = a4.y;
    As[kqA+2][mA] = a4.z; As[kqA+3][mA] = a4.w;
    *(float4*)&Bs[kB][nB] = *(const float4*)(B + (size_t)(k0 + kB)*N + bn + nB);
    __syncthreads();
    #pragma unroll
    for (int k = 0; k < 16; k++) {
      float4 av = *(float4*)&As[k][ty*4];
      float4 bv = *(float4*)&Bs[k][tx*4];
      float ar[4] = {av.x, av.y, av.z, av.w};
      float br[4] = {bv.x, bv.y, bv.z, bv.w};
      #pragma unroll
      for (int i = 0; i < 4; i++)
        #pragma unroll
        for (int j = 0; j < 4; j++)
          acc[i][j] += ar[i] * br[j];
    }
    __syncthreads();
  }
  float4 bi = *(const float4*)(bias + bn + tx*4);
  #pragma unroll
  for (int i = 0; i < 4; i++) {
    float4 o;
    o.x = acc[i][0] + bi.x; o.y = acc[i][1] + bi.y;
    o.z = acc[i][2] + bi.z; o.w = acc[i][3] + bi.w;
    *(float4*)(C + (size_t)(bm + ty*4 + i)*N + bn + tx*4) = o;
  }
}

// ------- P GEMM variant writing split bf16 hi/lo outputs --------------------
__global__ __launch_bounds__(256) void gemm_nn_bias_split(
    const float* __restrict__ A, const float* __restrict__ B,
    const float* __restrict__ bias,
    ushort_t* __restrict__ Phi, ushort_t* __restrict__ Plo,
    int M, int N, int K) {
  __shared__ float As[16][64];
  __shared__ float Bs[16][64];
  const int tid = threadIdx.x;
  const int bm = blockIdx.y * 64;
  const int bn = blockIdx.x * 64;
  const int tx = tid & 15, ty = tid >> 4;
  const int mA = tid >> 2, kqA = (tid & 3) * 4;
  const int kB = tid >> 4, nB = (tid & 15) * 4;
  float acc[4][4] = {{0.f}};
  for (int k0 = 0; k0 < K; k0 += 16) {
    float4 a4 = *(const float4*)(A + (size_t)(bm + mA)*K + k0 + kqA);
    As[kqA+0][mA] = a4.x; As[kqA+1][mA] = a4.y;
    As[kqA+2][mA] = a4.z; As[kqA+3][mA] = a4.w;
    *(float4*)&Bs[kB][nB] = *(const float4*)(B + (size_t)(k0 + kB)*N + bn + nB);
    __syncthreads();
    #pragma unroll
    for (int k = 0; k < 16; k++) {
      float4 av = *(float4*)&As[k][ty*4];
      float4 bv = *(float4*)&Bs[k][tx*4];
      float ar[4] = {av.x, av.y, av.z, av.w};
      float br[4] = {bv.x, bv.y, bv.z, bv.w};
      #pragma unroll
      for (int i = 0; i < 4; i++)
        #pragma unroll
        for (int j = 0; j < 4; j++)
          acc[i][j] += ar[i] * br[j];
    }
    __syncthreads();
  }
  float4 bi = *(const float4*)(bias + bn + tx*4);
  #pragma unroll
  for (int i = 0; i < 4; i++) {
    float o[4] = {acc[i][0] + bi.x, acc[i][1] + bi.y,
                  acc[i][2] + bi.z, acc[i][3] + bi.w};
    ushort4 h, l;
    h.x = f2bf(o[0]); l.x = f2bf(o[0] - bf2f(h.x));
    h.y = f2bf(o[1]); l.y = f2bf(o[1] - bf2f(h.y));
    h.z = f2bf(o[2]); l.z = f2bf(o[2] - bf2f(h.z));
    h.w = f2bf(o[3]); l.w = f2bf(o[3] - bf2f(h.w));
    const size_t off = (size_t)(bm + ty*4 + i)*N + bn + tx*4;
    *(ushort4*)(Phi + off) = h;
    *(ushort4*)(Plo + off) = l;
  }
}

// ------- logits GEMM, f32 fallback (128x128 tile, 8x8/thread) ---------------
__global__ __launch_bounds__(256) void gemm_nt_logits128(
    const float* __restrict__ A, const float* __restrict__ Bt,
    const int* __restrict__ ids, float* __restrict__ C) {
  const int K = EMBD, N = VOCAB;
  __shared__ float As[16][128];
  __shared__ float Bs[16][128];
  const int tid = threadIdx.x;
  const int bm = blockIdx.y * 128;
  const int bn = blockIdx.x * 128;
  const int tx = tid & 15, ty = tid >> 4;
  const int rL = tid >> 1, kL = (tid & 1) * 8;
  float acc[8][8] = {{0.f}};
  for (int k0 = 0; k0 < K; k0 += 16) {
    float4 a0 = *(const float4*)(A  + (size_t)(bm + rL)*K + k0 + kL);
    float4 a1 = *(const float4*)(A  + (size_t)(bm + rL)*K + k0 + kL + 4);
    float4 b0 = *(const float4*)(Bt + (size_t)(bn + rL)*K + k0 + kL);
    float4 b1 = *(const float4*)(Bt + (size_t)(bn + rL)*K + k0 + kL + 4);
    __syncthreads();
    As[kL+0][rL] = a0.x; As[kL+1][rL] = a0.y; As[kL+2][rL] = a0.z; As[kL+3][rL] = a0.w;
    As[kL+4][rL] = a1.x; As[kL+5][rL] = a1.y; As[kL+6][rL] = a1.z; As[kL+7][rL] = a1.w;
    Bs[kL+0][rL] = b0.x; Bs[kL+1][rL] = b0.y; Bs[kL+2][rL] = b0.z; Bs[kL+3][rL] = b0.w;
    Bs[kL+4][rL] = b1.x; Bs[kL+5][rL] = b1.y; Bs[kL+6][rL] = b1.z; Bs[kL+7][rL] = b1.w;
    __syncthreads();
    #pragma unroll
    for (int k = 0; k < 16; k++) {
      float4 av0 = *(float4*)&As[k][ty*4];
      float4 av1 = *(float4*)&As[k][64 + ty*4];
      float4 bv0 = *(float4*)&Bs[k][tx*4];
      float4 bv1 = *(float4*)&Bs[k][64 + tx*4];
      float ar[8] = {av0.x, av0.y, av0.z, av0.w, av1.x, av1.y, av1.z, av1.w};
      float br[8] = {bv0.x, bv0.y, bv0.z, bv0.w, bv1.x, bv1.y, bv1.z, bv1.w};
      #pragma unroll
      for (int i = 0; i < 8; i++)
        #pragma unroll
        for (int j = 0; j < 8; j++)
          acc[i][j] += ar[i] * br[j];
    }
  }
  #pragma unroll
  for (int i = 0; i < 8; i++) {
    const int row = bm + ((i < 4) ? (ty*4 + i) : (64 + ty*4 + i - 4));
    const bool mk = ids[row] != 0;
    float4 o0, o1;
    if (mk) {
      o0 = make_float4(acc[i][0], acc[i][1], acc[i][2], acc[i][3]);
      o1 = make_float4(acc[i][4], acc[i][5], acc[i][6], acc[i][7]);
    } else {
      o0 = make_float4((bn + tx*4 == 0) ? 1.f : 0.f, 0.f, 0.f, 0.f);
      o1 = make_float4(0.f, 0.f, 0.f, 0.f);
    }
    *(float4*)(C + (size_t)row*N + bn + tx*4)      = o0;
    *(float4*)(C + (size_t)row*N + bn + 64 + tx*4) = o1;
  }
}

// ------- logits GEMM, split-bf16 MFMA: C = P @ E^T, pad-masked --------------
// C = Phi.Ehi + Phi.Elo + Plo.Ehi (f32 accumulate). 64x128 tile, 4 waves,
// each wave 4 m-frags x 2 n-frags of 16x16x32. LDS tiles at pitch 40 bf16
// (2-way bank aliasing = free). Frag layouts: A/B lane l: row/col = l&15,
// k = (l>>4)*8 + j (contiguous 8); C/D: col = lane&15, row = (lane>>4)*4+reg.
__global__ __launch_bounds__(256, 1) void gemm_nt_logits_mfma(
    const ushort_t* __restrict__ Phi, const ushort_t* __restrict__ Plo,
    const ushort_t* __restrict__ Ehi, const ushort_t* __restrict__ Elo,
    const int* __restrict__ ids, float* __restrict__ C) {
  const int K = EMBD, N = VOCAB;
  __shared__ ushort_t Ah[64 * 40], Al[64 * 40];
  __shared__ ushort_t Bh[128 * 40], Bl[128 * 40];
  __shared__ int ids_s[64];
  const int tid  = threadIdx.x;
  const int lane = tid & 63;
  const int w    = tid >> 6;
  const int bm = blockIdx.y * 64;
  const int bn = blockIdx.x * 128;
  if (tid < 64) ids_s[tid] = ids[bm + tid];
  const int arow = tid >> 2, akc = (tid & 3) * 8;   // A loader
  const int brow = tid >> 1, bkc = (tid & 1) * 16;  // B loader
  const int kb = lane >> 4;     // k-block 0..3
  const int fr = lane & 15;     // frag row/col
  f32x4 zero = {0.f, 0.f, 0.f, 0.f};
  f32x4 acc[4][2];
  #pragma unroll
  for (int mf = 0; mf < 4; mf++)
    #pragma unroll
    for (int nf = 0; nf < 2; nf++) acc[mf][nf] = zero;

  for (int k0 = 0; k0 < K; k0 += 32) {
    uint4 va_h = *(const uint4*)(Phi + (size_t)(bm + arow)*K + k0 + akc);
    uint4 va_l = *(const uint4*)(Plo + (size_t)(bm + arow)*K + k0 + akc);
    uint4 vb_h0 = *(const uint4*)(Ehi + (size_t)(bn + brow)*K + k0 + bkc);
    uint4 vb_h1 = *(const uint4*)(Ehi + (size_t)(bn + brow)*K + k0 + bkc + 8);
    uint4 vb_l0 = *(const uint4*)(Elo + (size_t)(bn + brow)*K + k0 + bkc);
    uint4 vb_l1 = *(const uint4*)(Elo + (size_t)(bn + brow)*K + k0 + bkc + 8);
    __syncthreads();   // previous iteration's frag reads complete
    *(uint4*)&Ah[arow*40 + akc] = va_h;
    *(uint4*)&Al[arow*40 + akc] = va_l;
    *(uint4*)&Bh[brow*40 + bkc] = vb_h0;
    *(uint4*)&Bh[brow*40 + bkc + 8] = vb_h1;
    *(uint4*)&Bl[brow*40 + bkc] = vb_l0;
    *(uint4*)&Bl[brow*40 + bkc + 8] = vb_l1;
    __syncthreads();
    bf16x8 Afh[4], Afl[4], Bfh[2], Bfl[2];
    #pragma unroll
    for (int mf = 0; mf < 4; mf++) {
      Afh[mf] = *(const bf16x8*)&Ah[(mf*16 + fr)*40 + kb*8];
      Afl[mf] = *(const bf16x8*)&Al[(mf*16 + fr)*40 + kb*8];
    }
    #pragma unroll
    for (int nf = 0; nf < 2; nf++) {
      Bfh[nf] = *(const bf16x8*)&Bh[(w*32 + nf*16 + fr)*40 + kb*8];
      Bfl[nf] = *(const bf16x8*)&Bl[(w*32 + nf*16 + fr)*40 + kb*8];
    }
    #pragma unroll
    for (int mf = 0; mf < 4; mf++)
      #pragma unroll
      for (int nf = 0; nf < 2; nf++) {
        acc[mf][nf] = __builtin_amdgcn_mfma_f32_16x16x32_bf16(
            Afh[mf], Bfh[nf], acc[mf][nf], 0, 0, 0);
        acc[mf][nf] = __builtin_amdgcn_mfma_f32_16x16x32_bf16(
            Afh[mf], Bfl[nf], acc[mf][nf], 0, 0, 0);
        acc[mf][nf] = __builtin_amdgcn_mfma_f32_16x16x32_bf16(
            Afl[mf], Bfh[nf], acc[mf][nf], 0, 0, 0);
      }
  }
  const int rq = lane >> 4;     // row quad
  #pragma unroll
  for (int mf = 0; mf < 4; mf++) {
    #pragma unroll
    for (int r = 0; r < 4; r++) {
      const int rloc = mf*16 + rq*4 + r;
      const bool mk = ids_s[rloc] != 0;
      const size_t rbase = (size_t)(bm + rloc) * N;
      #pragma unroll
      for (int nf = 0; nf < 2; nf++) {
        const int col = bn + w*32 + nf*16 + fr;
        float v = acc[mf][nf][r];
        if (!mk) v = (col == 0) ? 1.f : 0.f;
        C[rbase + col] = v;
      }
    }
  }
}

// ---------------- fused 2-layer pipelined LSTM recurrence -------------------
// EXACT round-14/16 kernel (best measured: 3.35 ms, VGPR 256, zero spill).
__device__ __forceinline__ int rev5(int l) {
  return ((l & 1) << 4) | ((l & 2) << 2) | (l & 4) | ((l & 8) >> 2) | ((l & 16) >> 4);
}

#define HALVE(MASK, SH, HSZ)                          \
    { const int bit_ = (lane >> SH) & 1;              \
      _Pragma("unroll")                               \
      for (int j = 0; j < HSZ; j++) {                 \
        float snd = bit_ ? a[j] : a[j + HSZ];         \
        float kep = bit_ ? a[j + HSZ] : a[j];         \
        a[j] = kep + __shfl_xor(snd, MASK);           \
      } }

__global__ __launch_bounds__(256, 1) void lstm_fused(
    const float* __restrict__ Z0, const float* __restrict__ Wr0T,
    const float* __restrict__ Wk1T, const float* __restrict__ Wr1T,
    const float* __restrict__ bias1, const int* __restrict__ ids,
    float* __restrict__ H1, float* __restrict__ H0full,
    unsigned* __restrict__ flgA, unsigned* __restrict__ flgB) {
  __shared__ float wk[32][1024];
  __shared__ float hs[NBAT * HIDD];
  __shared__ float z_s[4][64];
  __shared__ float zc[128];
  const int tid  = threadIdx.x;
  const int lane = tid & 63;
  const int w    = tid >> 6;
  const int ccH  = tid >> 7;
  const int part = tid & 127;

  if (blockIdx.x < ABLK) {
    const int hbase = blockIdx.x * 8;
    float4 Wf[16], Wg[16];
    #pragma unroll
    for (int cl = 0; cl < 16; cl++) {
      const int cc = ccH * 16 + cl;
      const int g  = cc >> 3, d = cc & 7;
      const size_t col = (size_t)(g * HIDD + hbase + d);
      Wf[cl] = *(const float4*)(Wr0T + col * HIDD + 4 * part);
      Wg[cl] = *(const float4*)(Wr0T + col * HIDD + 512 + 4 * part);
    }
    float c_reg = 0.f, h_reg = 0.f;
    __syncthreads();

    for (int t = 0; t < SLEN; t++) {
      float pz0 = 0.f, pz1 = 0.f, pz2 = 0.f, pz3 = 0.f;
      int pmk = 0;
      if (tid < 32) {
        const int b = tid >> 3, d = tid & 7;
        const float* zrow = Z0 + (size_t)(b*SLEN + t) * GATE4 + hbase + d;
        pz0 = zrow[0];      pz1 = zrow[HIDD];
        pz2 = zrow[2*HIDD]; pz3 = zrow[3*HIDD];
        pmk = ids[b*SLEN + t];
      }
      float4 ha[NBAT], hb[NBAT];
      if (t > 0) {
        if (tid < ABLK) {
          while (AL(flgA + tid * 16) < (unsigned)t)
            __builtin_amdgcn_s_sleep(1);
        }
        __syncthreads();
        const u64* src = (const u64*)H0full + (size_t)(t - 1) * 2048;
        u64 v[8];
        #pragma unroll
        for (int r = 0; r < 8; r++)
          v[r] = AL(src + tid + (r << 8));
        #pragma unroll
        for (int r = 0; r < 8; r++)
          ((u64*)hs)[tid + (r << 8)] = v[r];
        __syncthreads();
        #pragma unroll
        for (int b = 0; b < NBAT; b++) {
          ha[b] = *(const float4*)(hs + b*HIDD + 4*part);
          hb[b] = *(const float4*)(hs + b*HIDD + 512 + 4*part);
        }
      } else {
        #pragma unroll
        for (int b = 0; b < NBAT; b++) {
          ha[b] = make_float4(0.f, 0.f, 0.f, 0.f);
          hb[b] = make_float4(0.f, 0.f, 0.f, 0.f);
        }
      }
      float a[64];
      #pragma unroll
      for (int cl = 0; cl < 16; cl++)
        #pragma unroll
        for (int b = 0; b < NBAT; b++)
          a[cl*4 + b] = Wf[cl].x*ha[b].x + Wf[cl].y*ha[b].y
                      + Wf[cl].z*ha[b].z + Wf[cl].w*ha[b].w
                      + Wg[cl].x*hb[b].x + Wg[cl].y*hb[b].y
                      + Wg[cl].z*hb[b].z + Wg[cl].w*hb[b].w;
      #pragma unroll
      for (int i = 0; i < 64; i++) a[i] += __shfl_xor(a[i], 32);
      HALVE(1, 0, 32) HALVE(2, 1, 16) HALVE(4, 2, 8) HALVE(8, 3, 4) HALVE(16, 4, 2)
      if (lane < 32) {
        z_s[w][rev5(lane)*2 + 0] = a[0];
        z_s[w][rev5(lane)*2 + 1] = a[1];
      }
      __syncthreads();
      if (tid < 128) {
        const int cc = tid >> 2, b = tid & 3;
        const int cH = cc >> 4, i = ((cc & 15) << 2) | b;
        zc[tid] = z_s[2*cH][i] + z_s[2*cH + 1][i];
      }
      __syncthreads();
      if (tid < 32) {
        const int b = tid >> 3, d = tid & 7;
        const float zi = zc[((0*8 + d) << 2) + b] + pz0;
        const float zf = zc[((1*8 + d) << 2) + b] + pz1;
        const float zg = zc[((2*8 + d) << 2) + b] + pz2;
        const float zo = zc[((3*8 + d) << 2) + b] + pz3;
        const float ig = 1.f / (1.f + expf(-zi));
        const float fg = 1.f / (1.f + expf(-zf));
        const float gg = tanhf(zg);
        const float og = 1.f / (1.f + expf(-zo));
        const float cn = fg * c_reg + ig * gg;
        const float hn = og * tanhf(cn);
        const bool mk = pmk != 0;
        const float ho = mk ? hn : h_reg;
        c_reg = mk ? cn : c_reg;
        h_reg = ho;
        AS(H0full + (size_t)t * (NBAT*HIDD) + b*HIDD + hbase + d, ho);
      }
      if (w == 0) {
        asm volatile("s_waitcnt vmcnt(0)" ::: "memory");
        if (tid == 0)
          AS(flgA + blockIdx.x * 16, (unsigned)(t + 1));
      }
      __syncthreads();
    }
  } else {
    const int bid = blockIdx.x - ABLK;
    const int ub  = bid * 8;
    for (int i = tid; i < 32 * 256; i += 256) {
      const int c2 = i >> 8, k4 = i & 255;
      const size_t col = (size_t)((c2 >> 3) * HIDD + ub + (c2 & 7));
      *(float4*)&wk[c2][k4 * 4] = *(const float4*)(Wk1T + col * HIDD + 4 * k4);
    }
    float4 Rf[16], Rg[16];
    #pragma unroll
    for (int cl = 0; cl < 16; cl++) {
      const int cc = ccH * 16 + cl;
      const int g  = cc >> 3, d = cc & 7;
      const size_t col = (size_t)(g * HIDD + ub + d);
      Rf[cl] = *(const float4*)(Wr1T + col * HIDD + 4 * part);
      Rg[cl] = *(const float4*)(Wr1T + col * HIDD + 512 + 4 * part);
    }
    float pbi = 0.f, pbf = 0.f, pbg = 0.f, pbo = 0.f;
    if (tid < 32) {
      const int d = tid & 7;
      pbi = bias1[0*HIDD + ub + d];
      pbf = bias1[1*HIDD + ub + d];
      pbg = bias1[2*HIDD + ub + d];
      pbo = bias1[3*HIDD + ub + d];
    }
    float c_reg = 0.f, h_reg = 0.f;
    __syncthreads();

    for (int t = 0; t < SLEN; t++) {
      int pmk = 0;
      if (tid < 32) pmk = ids[(tid >> 3) * SLEN + t];
      if (tid < 128) {
        while (AL(flgA + tid * 16) < (unsigned)(t + 1))
          __builtin_amdgcn_s_sleep(1);
      }
      __syncthreads();
      {
        const u64* h0p = (const u64*)H0full + (size_t)t * 2048;
        u64 v[8];
        #pragma unroll
        for (int r = 0; r < 8; r++)
          v[r] = AL(h0p + tid + (r << 8));
        #pragma unroll
        for (int r = 0; r < 8; r++)
          ((u64*)hs)[tid + (r << 8)] = v[r];
      }
      __syncthreads();
      float4 xa[NBAT], xb[NBAT];
      #pragma unroll
      for (int b = 0; b < NBAT; b++) {
        xa[b] = *(const float4*)(hs + b*HIDD + 4*part);
        xb[b] = *(const float4*)(hs + b*HIDD + 512 + 4*part);
      }
      float a[64];
      #pragma unroll
      for (int cl = 0; cl < 16; cl++) {
        const int c2 = ccH * 16 + cl;
        const float4 kf = *(const float4*)&wk[c2][4 * part];
        const float4 kg = *(const float4*)&wk[c2][512 + 4 * part];
        #pragma unroll
        for (int b = 0; b < NBAT; b++) {
          a[cl*4 + b] = kf.x*xa[b].x + kf.y*xa[b].y + kf.z*xa[b].z + kf.w*xa[b].w
                      + kg.x*xb[b].x + kg.y*xb[b].y + kg.z*xb[b].z + kg.w*xb[b].w;
        }
      }
      if (t > 0) {
        if (tid < 128) {
          while (AL(flgB + tid * 16) < (unsigned)t)
            __builtin_amdgcn_s_sleep(1);
        }
        __syncthreads();
        {
          u64 v[8];
          #pragma unroll
          for (int r = 0; r < 8; r++) {
            const int idx = tid + (r << 8);
            const int b = idx >> 9, off = idx & 511;
            v[r] = AL((const u64*)H1 + (size_t)(b*SLEN + t - 1) * 512 + off);
          }
          #pragma unroll
          for (int r = 0; r < 8; r++)
            ((u64*)hs)[tid + (r << 8)] = v[r];
        }
        __syncthreads();
        float4 ya[NBAT], yb[NBAT];
        #pragma unroll
        for (int b = 0; b < NBAT; b++) {
          ya[b] = *(const float4*)(hs + b*HIDD + 4*part);
          yb[b] = *(const float4*)(hs + b*HIDD + 512 + 4*part);
        }
        #pragma unroll
        for (int cl = 0; cl < 16; cl++) {
          #pragma unroll
          for (int b = 0; b < NBAT; b++) {
            a[cl*4 + b] += Rf[cl].x*ya[b].x + Rf[cl].y*ya[b].y
                         + Rf[cl].z*ya[b].z + Rf[cl].w*ya[b].w
                         + Rg[cl].x*yb[b].x + Rg[cl].y*yb[b].y
                         + Rg[cl].z*yb[b].z + Rg[cl].w*yb[b].w;
          }
        }
      }
      #pragma unroll
      for (int i = 0; i < 64; i++) a[i] += __shfl_xor(a[i], 32);
      HALVE(1, 0, 32) HALVE(2, 1, 16) HALVE(4, 2, 8) HALVE(8, 3, 4) HALVE(16, 4, 2)
      if (lane < 32) {
        z_s[w][rev5(lane)*2 + 0] = a[0];
        z_s[w][rev5(lane)*2 + 1] = a[1];
      }
      __syncthreads();
      if (tid < 128) {
        const int cc = tid >> 2, b = tid & 3;
        const int cH = cc >> 4, i = ((cc & 15) << 2) | b;
        zc[tid] = z_s[2*cH][i] + z_s[2*cH + 1][i];
      }
      __syncthreads();
      if (tid < 32) {
        const int b = tid >> 3, d = tid & 7;
        const float zi = zc[((0*8 + d) << 2) + b] + pbi;
        const float zf = zc[((1*8 + d) << 2) + b] + pbf;
        const float zg = zc[((2*8 + d) << 2) + b] + pbg;
        const float zo = zc[((3*8 + d) << 2) + b] + pbo;
        const float ig = 1.f / (1.f + expf(-zi));
        const float fg = 1.f / (1.f + expf(-zf));
        const float gg = tanhf(zg);
        const float og = 1.f / (1.f + expf(-zo));
        const float cn = fg * c_reg + ig * gg;
        const float hn = og * tanhf(cn);
        const bool mk = pmk != 0;
        const float ho = mk ? hn : h_reg;
        c_reg = mk ? cn : c_reg;
        h_reg = ho;
        AS(H1 + (size_t)(b*SLEN + t) * HIDD + ub + d, ho);
      }
      if (w == 0) {
        asm volatile("s_waitcnt vmcnt(0)" ::: "memory");
        if (tid == 0)
          AS(flgB + bid * 16, (unsigned)(t + 1));
      }
      __syncthreads();
    }
  }
}
#undef HALVE

extern "C" void kernel_launch(void* const* d_in, const int* in_sizes, int n_in,
                              void* d_out, int out_size, void* d_ws, size_t ws_size,
                              hipStream_t stream) {
  const int*   ids = (const int*)  d_in[0];
  const float* emb = (const float*)d_in[1];
  const float* Wk0 = (const float*)d_in[2];
  const float* Wr0 = (const float*)d_in[3];
  const float* b0  = (const float*)d_in[4];
  const float* Wk1 = (const float*)d_in[5];
  const float* Wr1 = (const float*)d_in[6];
  const float* b1  = (const float*)d_in[7];
  const float* Wp  = (const float*)d_in[8];
  const float* bp  = (const float*)d_in[9];
  float* out = (float*)d_out;

  // DEAD-before-logits intermediates in the head of d_out.
  float* Z      = out;                  // [2048, 4096]
  float* H1     = out + 8388608;        // [2048, 1024]
  float* Wr0T   = out + 10485760;       // [4096][1024]
  float* Wr1T   = out + 14680064;       // [4096][1024]
  float* Wk1T   = out + 18874368;       // [4096][1024]
  float* H0full = out + 23068672;       // [512][4096]
  // d_ws layout (mfma path): flags 16KB | Phi 2MB | Plo 2MB | Ehi 32.8MB | Elo
  unsigned* flgA = (unsigned*)d_ws;
  unsigned* flgB = (unsigned*)d_ws + 2048;
  char* wsb = (char*)d_ws;
  ushort_t* Phi = (ushort_t*)(wsb + 16384);
  ushort_t* Plo = (ushort_t*)(wsb + 2113536);
  ushort_t* Ehi = (ushort_t*)(wsb + 4210688);
  ushort_t* Elo = (ushort_t*)(wsb + 36978688);
  const size_t WS_NEED = 69746688ull;
  const bool use_mfma = ws_size >= WS_NEED;
  float* P = ((float*)d_ws) + 4096;     // fallback path only (4 MB)

  hipMemsetAsync(d_ws, 0, 16384, stream);  // zero both flag arrays
  if (use_mfma)
    split_bf16_k<<<(VOCAB*EMBD/4 + 255)/256, 256, 0, stream>>>(emb, Ehi, Elo,
                                                              VOCAB*EMBD/4);
  transpose_k<<<dim3(128, 32), 256, 0, stream>>>(Wr0, Wr0T);
  transpose_k<<<dim3(128, 32), 256, 0, stream>>>(Wr1, Wr1T);
  transpose_k<<<dim3(128, 32), 256, 0, stream>>>(Wk1, Wk1T);
  gemm_nn_emb128<<<dim3(32, 16), 256, 0, stream>>>(ids, emb, Wk0, b0, Z);
  lstm_fused<<<ABLK + BBLK, 256, 0, stream>>>(Z, Wr0T, Wk1T, Wr1T, b1, ids,
                                              H1, H0full, flgA, flgB);
  if (use_mfma) {
    gemm_nn_bias_split<<<dim3(8, 32), 256, 0, stream>>>(H1, Wp, bp, Phi, Plo,
                                                        2048, 512, 1024);
    gemm_nt_logits_mfma<<<dim3(250, 32), 256, 0, stream>>>(Phi, Plo, Ehi, Elo,
                                                           ids, out);
  } else {
    gemm_nn_bias<<<dim3(8, 32), 256, 0, stream>>>(H1, Wp, bp, P, 2048, 512, 1024);
    gemm_nt_logits128<<<dim3(250, 16), 256, 0, stream>>>(P, emb, ids, out);
  }
}

// Round 18
// 3866.297 us; speedup vs baseline: 1.1026x; 1.0030x over previous
//
#include <hip/hip_runtime.h>

#define VOCAB 32000
#define EMBD  512
#define HIDD  1024
#define SLEN  512
#define NBAT  4
#define GATE4 4096   // 4*HIDD
#define ABLK  128    // layer-0 blocks, 8 units each
#define BBLK  128    // layer-1 blocks, 8 units each (Wk1 in LDS, Wr1 in regs)

typedef unsigned long long u64;
typedef unsigned short ushort_t;
typedef __attribute__((ext_vector_type(8))) short bf16x8;
typedef __attribute__((ext_vector_type(4))) float f32x4;

#define AL(p) __hip_atomic_load((p), __ATOMIC_RELAXED, __HIP_MEMORY_SCOPE_AGENT)
#define AS(p, v) __hip_atomic_store((p), (v), __ATOMIC_RELAXED, __HIP_MEMORY_SCOPE_AGENT)

__device__ __forceinline__ ushort_t f2bf(float x) {   // round-to-nearest-even
  unsigned u = __float_as_uint(x);
  unsigned r = u + 0x7fffu + ((u >> 16) & 1u);
  return (ushort_t)(r >> 16);
}
__device__ __forceinline__ float bf2f(ushort_t h) {
  return __uint_as_float((unsigned)h << 16);
}

// ---------------- 32x32 tiled transpose: [1024][4096] -> [4096][1024] -------
__global__ __launch_bounds__(256) void transpose_k(const float* __restrict__ src,
                                                   float* __restrict__ dst) {
  __shared__ float t[32][33];
  const int bx = blockIdx.x * 32;
  const int by = blockIdx.y * 32;
  const int r0 = threadIdx.x >> 5;
  const int c  = threadIdx.x & 31;
  #pragma unroll
  for (int i = 0; i < 4; i++) {
    const int r = r0 + i*8;
    t[r][c] = src[(size_t)(by + r)*GATE4 + bx + c];
  }
  __syncthreads();
  #pragma unroll
  for (int i = 0; i < 4; i++) {
    const int rw = r0 + i*8;
    dst[(size_t)(bx + rw)*HIDD + by + c] = t[c][rw];
  }
}

// -------- split f32 -> (bf16 hi, bf16 lo), vectorized by float4 ----------
__global__ __launch_bounds__(256) void split_bf16_k(
    const float* __restrict__ src, ushort_t* __restrict__ hi,
    ushort_t* __restrict__ lo, int n4) {
  const int i = blockIdx.x * 256 + threadIdx.x;
  if (i >= n4) return;
  float4 v = ((const float4*)src)[i];
  ushort4 h, l;
  h.x = f2bf(v.x); l.x = f2bf(v.x - bf2f(h.x));
  h.y = f2bf(v.y); l.y = f2bf(v.y - bf2f(h.y));
  h.z = f2bf(v.z); l.z = f2bf(v.z - bf2f(h.z));
  h.w = f2bf(v.w); l.w = f2bf(v.w - bf2f(h.w));
  ((ushort4*)hi)[i] = h;
  ((ushort4*)lo)[i] = l;
}

// -------- layer-0 input GEMM with fused embedding gather, 128x128 tile ------
__global__ __launch_bounds__(256) void gemm_nn_emb128(
    const int* __restrict__ ids, const float* __restrict__ emb,
    const float* __restrict__ B, const float* __restrict__ bias,
    float* __restrict__ C) {
  const int N = GATE4, K = EMBD;
  __shared__ float As[16][128];
  __shared__ float Bs[16][128];
  const int tid = threadIdx.x;
  const int bm = blockIdx.y * 128;
  const int bn = blockIdx.x * 128;
  const int tx = tid & 15, ty = tid >> 4;
  const int rL = tid >> 1, kL = (tid & 1) * 8;
  const int kB = tid >> 4, nB = (tid & 15) * 8;
  const int rid = ids[bm + rL];
  float acc[8][8] = {{0.f}};
  for (int k0 = 0; k0 < K; k0 += 16) {
    float4 a0 = *(const float4*)(emb + (size_t)rid*EMBD + k0 + kL);
    float4 a1 = *(const float4*)(emb + (size_t)rid*EMBD + k0 + kL + 4);
    float4 b0 = *(const float4*)(B + (size_t)(k0 + kB)*N + bn + nB);
    float4 b1 = *(const float4*)(B + (size_t)(k0 + kB)*N + bn + nB + 4);
    __syncthreads();
    As[kL+0][rL] = a0.x; As[kL+1][rL] = a0.y; As[kL+2][rL] = a0.z; As[kL+3][rL] = a0.w;
    As[kL+4][rL] = a1.x; As[kL+5][rL] = a1.y; As[kL+6][rL] = a1.z; As[kL+7][rL] = a1.w;
    *(float4*)&Bs[kB][nB]     = b0;
    *(float4*)&Bs[kB][nB + 4] = b1;
    __syncthreads();
    #pragma unroll
    for (int k = 0; k < 16; k++) {
      float4 av0 = *(float4*)&As[k][ty*4];
      float4 av1 = *(float4*)&As[k][64 + ty*4];
      float4 bv0 = *(float4*)&Bs[k][tx*4];
      float4 bv1 = *(float4*)&Bs[k][64 + tx*4];
      float ar[8] = {av0.x, av0.y, av0.z, av0.w, av1.x, av1.y, av1.z, av1.w};
      float br[8] = {bv0.x, bv0.y, bv0.z, bv0.w, bv1.x, bv1.y, bv1.z, bv1.w};
      #pragma unroll
      for (int i = 0; i < 8; i++)
        #pragma unroll
        for (int j = 0; j < 8; j++)
          acc[i][j] += ar[i] * br[j];
    }
  }
  float4 bi0 = *(const float4*)(bias + bn + tx*4);
  float4 bi1 = *(const float4*)(bias + bn + 64 + tx*4);
  #pragma unroll
  for (int i = 0; i < 8; i++) {
    const int row = bm + ((i < 4) ? (ty*4 + i) : (64 + ty*4 + i - 4));
    float4 o0 = make_float4(acc[i][0] + bi0.x, acc[i][1] + bi0.y,
                            acc[i][2] + bi0.z, acc[i][3] + bi0.w);
    float4 o1 = make_float4(acc[i][4] + bi1.x, acc[i][5] + bi1.y,
                            acc[i][6] + bi1.z, acc[i][7] + bi1.w);
    *(float4*)(C + (size_t)row*N + bn + tx*4)      = o0;
    *(float4*)(C + (size_t)row*N + bn + 64 + tx*4) = o1;
  }
}

// ---------------- f32 tiled GEMM: C = A@B + bias (64x64) ----------------
__global__ __launch_bounds__(256) void gemm_nn_bias(
    const float* __restrict__ A, const float* __restrict__ B,
    const float* __restrict__ bias, float* __restrict__ C,
    int M, int N, int K) {
  __shared__ float As[16][64];
  __shared__ float Bs[16][64];
  const int tid = threadIdx.x;
  const int bm = blockIdx.y * 64;
  const int bn = blockIdx.x * 64;
  const int tx = tid & 15, ty = tid >> 4;
  const int mA = tid >> 2, kqA = (tid & 3) * 4;
  const int kB = tid >> 4, nB = (tid & 15) * 4;
  float acc[4][4] = {{0.f}};
  for (int k0 = 0; k0 < K; k0 += 16) {
    float4 a4 = *(const float4*)(A + (size_t)(bm + mA)*K + k0 + kqA);
    As[kqA+0][mA] = a4.x; As[kqA+1][mA] = a4.y;
    As[kqA+2][mA] = a4.z; As[kqA+3][mA] = a4.w;
    *(float4*)&Bs[kB][nB] = *(const float4*)(B + (size_t)(k0 + kB)*N + bn + nB);
    __syncthreads();
    #pragma unroll
    for (int k = 0; k < 16; k++) {
      float4 av = *(float4*)&As[k][ty*4];
      float4 bv = *(float4*)&Bs[k][tx*4];
      float ar[4] = {av.x, av.y, av.z, av.w};
      float br[4] = {bv.x, bv.y, bv.z, bv.w};
      #pragma unroll
      for (int i = 0; i < 4; i++)
        #pragma unroll
        for (int j = 0; j < 4; j++)
          acc[i][j] += ar[i] * br[j];
    }
    __syncthreads();
  }
  float4 bi = *(const float4*)(bias + bn + tx*4);
  #pragma unroll
  for (int i = 0; i < 4; i++) {
    float4 o;
    o.x = acc[i][0] + bi.x; o.y = acc[i][1] + bi.y;
    o.z = acc[i][2] + bi.z; o.w = acc[i][3] + bi.w;
    *(float4*)(C + (size_t)(bm + ty*4 + i)*N + bn + tx*4) = o;
  }
}

// ------- P GEMM variant writing split bf16 hi/lo outputs --------------------
__global__ __launch_bounds__(256) void gemm_nn_bias_split(
    const float* __restrict__ A, const float* __restrict__ B,
    const float* __restrict__ bias,
    ushort_t* __restrict__ Phi, ushort_t* __restrict__ Plo,
    int M, int N, int K) {
  __shared__ float As[16][64];
  __shared__ float Bs[16][64];
  const int tid = threadIdx.x;
  const int bm = blockIdx.y * 64;
  const int bn = blockIdx.x * 64;
  const int tx = tid & 15, ty = tid >> 4;
  const int mA = tid >> 2, kqA = (tid & 3) * 4;
  const int kB = tid >> 4, nB = (tid & 15) * 4;
  float acc[4][4] = {{0.f}};
  for (int k0 = 0; k0 < K; k0 += 16) {
    float4 a4 = *(const float4*)(A + (size_t)(bm + mA)*K + k0 + kqA);
    As[kqA+0][mA] = a4.x; As[kqA+1][mA] = a4.y;
    As[kqA+2][mA] = a4.z; As[kqA+3][mA] = a4.w;
    *(float4*)&Bs[kB][nB] = *(const float4*)(B + (size_t)(k0 + kB)*N + bn + nB);
    __syncthreads();
    #pragma unroll
    for (int k = 0; k < 16; k++) {
      float4 av = *(float4*)&As[k][ty*4];
      float4 bv = *(float4*)&Bs[k][tx*4];
      float ar[4] = {av.x, av.y, av.z, av.w};
      float br[4] = {bv.x, bv.y, bv.z, bv.w};
      #pragma unroll
      for (int i = 0; i < 4; i++)
        #pragma unroll
        for (int j = 0; j < 4; j++)
          acc[i][j] += ar[i] * br[j];
    }
    __syncthreads();
  }
  float4 bi = *(const float4*)(bias + bn + tx*4);
  #pragma unroll
  for (int i = 0; i < 4; i++) {
    float o[4] = {acc[i][0] + bi.x, acc[i][1] + bi.y,
                  acc[i][2] + bi.z, acc[i][3] + bi.w};
    ushort4 h, l;
    h.x = f2bf(o[0]); l.x = f2bf(o[0] - bf2f(h.x));
    h.y = f2bf(o[1]); l.y = f2bf(o[1] - bf2f(h.y));
    h.z = f2bf(o[2]); l.z = f2bf(o[2] - bf2f(h.z));
    h.w = f2bf(o[3]); l.w = f2bf(o[3] - bf2f(h.w));
    const size_t off = (size_t)(bm + ty*4 + i)*N + bn + tx*4;
    *(ushort4*)(Phi + off) = h;
    *(ushort4*)(Plo + off) = l;
  }
}

// ------- logits GEMM, f32 fallback (128x128 tile, 8x8/thread) ---------------
__global__ __launch_bounds__(256) void gemm_nt_logits128(
    const float* __restrict__ A, const float* __restrict__ Bt,
    const int* __restrict__ ids, float* __restrict__ C) {
  const int K = EMBD, N = VOCAB;
  __shared__ float As[16][128];
  __shared__ float Bs[16][128];
  const int tid = threadIdx.x;
  const int bm = blockIdx.y * 128;
  const int bn = blockIdx.x * 128;
  const int tx = tid & 15, ty = tid >> 4;
  const int rL = tid >> 1, kL = (tid & 1) * 8;
  float acc[8][8] = {{0.f}};
  for (int k0 = 0; k0 < K; k0 += 16) {
    float4 a0 = *(const float4*)(A  + (size_t)(bm + rL)*K + k0 + kL);
    float4 a1 = *(const float4*)(A  + (size_t)(bm + rL)*K + k0 + kL + 4);
    float4 b0 = *(const float4*)(Bt + (size_t)(bn + rL)*K + k0 + kL);
    float4 b1 = *(const float4*)(Bt + (size_t)(bn + rL)*K + k0 + kL + 4);
    __syncthreads();
    As[kL+0][rL] = a0.x; As[kL+1][rL] = a0.y; As[kL+2][rL] = a0.z; As[kL+3][rL] = a0.w;
    As[kL+4][rL] = a1.x; As[kL+5][rL] = a1.y; As[kL+6][rL] = a1.z; As[kL+7][rL] = a1.w;
    Bs[kL+0][rL] = b0.x; Bs[kL+1][rL] = b0.y; Bs[kL+2][rL] = b0.z; Bs[kL+3][rL] = b0.w;
    Bs[kL+4][rL] = b1.x; Bs[kL+5][rL] = b1.y; Bs[kL+6][rL] = b1.z; Bs[kL+7][rL] = b1.w;
    __syncthreads();
    #pragma unroll
    for (int k = 0; k < 16; k++) {
      float4 av0 = *(float4*)&As[k][ty*4];
      float4 av1 = *(float4*)&As[k][64 + ty*4];
      float4 bv0 = *(float4*)&Bs[k][tx*4];
      float4 bv1 = *(float4*)&Bs[k][64 + tx*4];
      float ar[8] = {av0.x, av0.y, av0.z, av0.w, av1.x, av1.y, av1.z, av1.w};
      float br[8] = {bv0.x, bv0.y, bv0.z, bv0.w, bv1.x, bv1.y, bv1.z, bv1.w};
      #pragma unroll
      for (int i = 0; i < 8; i++)
        #pragma unroll
        for (int j = 0; j < 8; j++)
          acc[i][j] += ar[i] * br[j];
    }
  }
  #pragma unroll
  for (int i = 0; i < 8; i++) {
    const int row = bm + ((i < 4) ? (ty*4 + i) : (64 + ty*4 + i - 4));
    const bool mk = ids[row] != 0;
    float4 o0, o1;
    if (mk) {
      o0 = make_float4(acc[i][0], acc[i][1], acc[i][2], acc[i][3]);
      o1 = make_float4(acc[i][4], acc[i][5], acc[i][6], acc[i][7]);
    } else {
      o0 = make_float4((bn + tx*4 == 0) ? 1.f : 0.f, 0.f, 0.f, 0.f);
      o1 = make_float4(0.f, 0.f, 0.f, 0.f);
    }
    *(float4*)(C + (size_t)row*N + bn + tx*4)      = o0;
    *(float4*)(C + (size_t)row*N + bn + 64 + tx*4) = o1;
  }
}

// ------- logits GEMM, split-bf16 MFMA: C = P @ E^T, pad-masked --------------
__global__ __launch_bounds__(256, 1) void gemm_nt_logits_mfma(
    const ushort_t* __restrict__ Phi, const ushort_t* __restrict__ Plo,
    const ushort_t* __restrict__ Ehi, const ushort_t* __restrict__ Elo,
    const int* __restrict__ ids, float* __restrict__ C) {
  const int K = EMBD, N = VOCAB;
  __shared__ ushort_t Ah[64 * 40], Al[64 * 40];
  __shared__ ushort_t Bh[128 * 40], Bl[128 * 40];
  __shared__ int ids_s[64];
  const int tid  = threadIdx.x;
  const int lane = tid & 63;
  const int w    = tid >> 6;
  const int bm = blockIdx.y * 64;
  const int bn = blockIdx.x * 128;
  if (tid < 64) ids_s[tid] = ids[bm + tid];
  const int arow = tid >> 2, akc = (tid & 3) * 8;   // A loader
  const int brow = tid >> 1, bkc = (tid & 1) * 16;  // B loader
  const int kb = lane >> 4;     // k-block 0..3
  const int fr = lane & 15;     // frag row/col
  f32x4 zero = {0.f, 0.f, 0.f, 0.f};
  f32x4 acc[4][2];
  #pragma unroll
  for (int mf = 0; mf < 4; mf++)
    #pragma unroll
    for (int nf = 0; nf < 2; nf++) acc[mf][nf] = zero;

  for (int k0 = 0; k0 < K; k0 += 32) {
    uint4 va_h = *(const uint4*)(Phi + (size_t)(bm + arow)*K + k0 + akc);
    uint4 va_l = *(const uint4*)(Plo + (size_t)(bm + arow)*K + k0 + akc);
    uint4 vb_h0 = *(const uint4*)(Ehi + (size_t)(bn + brow)*K + k0 + bkc);
    uint4 vb_h1 = *(const uint4*)(Ehi + (size_t)(bn + brow)*K + k0 + bkc + 8);
    uint4 vb_l0 = *(const uint4*)(Elo + (size_t)(bn + brow)*K + k0 + bkc);
    uint4 vb_l1 = *(const uint4*)(Elo + (size_t)(bn + brow)*K + k0 + bkc + 8);
    __syncthreads();   // previous iteration's frag reads complete
    *(uint4*)&Ah[arow*40 + akc] = va_h;
    *(uint4*)&Al[arow*40 + akc] = va_l;
    *(uint4*)&Bh[brow*40 + bkc] = vb_h0;
    *(uint4*)&Bh[brow*40 + bkc + 8] = vb_h1;
    *(uint4*)&Bl[brow*40 + bkc] = vb_l0;
    *(uint4*)&Bl[brow*40 + bkc + 8] = vb_l1;
    __syncthreads();
    bf16x8 Afh[4], Afl[4], Bfh[2], Bfl[2];
    #pragma unroll
    for (int mf = 0; mf < 4; mf++) {
      Afh[mf] = *(const bf16x8*)&Ah[(mf*16 + fr)*40 + kb*8];
      Afl[mf] = *(const bf16x8*)&Al[(mf*16 + fr)*40 + kb*8];
    }
    #pragma unroll
    for (int nf = 0; nf < 2; nf++) {
      Bfh[nf] = *(const bf16x8*)&Bh[(w*32 + nf*16 + fr)*40 + kb*8];
      Bfl[nf] = *(const bf16x8*)&Bl[(w*32 + nf*16 + fr)*40 + kb*8];
    }
    #pragma unroll
    for (int mf = 0; mf < 4; mf++)
      #pragma unroll
      for (int nf = 0; nf < 2; nf++) {
        acc[mf][nf] = __builtin_amdgcn_mfma_f32_16x16x32_bf16(
            Afh[mf], Bfh[nf], acc[mf][nf], 0, 0, 0);
        acc[mf][nf] = __builtin_amdgcn_mfma_f32_16x16x32_bf16(
            Afh[mf], Bfl[nf], acc[mf][nf], 0, 0, 0);
        acc[mf][nf] = __builtin_amdgcn_mfma_f32_16x16x32_bf16(
            Afl[mf], Bfh[nf], acc[mf][nf], 0, 0, 0);
      }
  }
  const int rq = lane >> 4;     // row quad
  #pragma unroll
  for (int mf = 0; mf < 4; mf++) {
    #pragma unroll
    for (int r = 0; r < 4; r++) {
      const int rloc = mf*16 + rq*4 + r;
      const bool mk = ids_s[rloc] != 0;
      const size_t rbase = (size_t)(bm + rloc) * N;
      #pragma unroll
      for (int nf = 0; nf < 2; nf++) {
        const int col = bn + w*32 + nf*16 + fr;
        float v = acc[mf][nf][r];
        if (!mk) v = (col == 0) ? 1.f : 0.f;
        C[rbase + col] = v;
      }
    }
  }
}

// ---------------- fused 2-layer pipelined LSTM recurrence -------------------
// Round-14/16 kernel, ONE change: poll backoff s_sleep(1) -> s_sleep(4)
// (~256-cycle cadence) in all three poll loops, cutting the MALL poll-traffic
// storm that contends with payload gathers (FETCH showed ~95MB of poll
// re-reads per dispatch).
__device__ __forceinline__ int rev5(int l) {
  return ((l & 1) << 4) | ((l & 2) << 2) | (l & 4) | ((l & 8) >> 2) | ((l & 16) >> 4);
}

#define HALVE(MASK, SH, HSZ)                          \
    { const int bit_ = (lane >> SH) & 1;              \
      _Pragma("unroll")                               \
      for (int j = 0; j < HSZ; j++) {                 \
        float snd = bit_ ? a[j] : a[j + HSZ];         \
        float kep = bit_ ? a[j + HSZ] : a[j];         \
        a[j] = kep + __shfl_xor(snd, MASK);           \
      } }

__global__ __launch_bounds__(256, 1) void lstm_fused(
    const float* __restrict__ Z0, const float* __restrict__ Wr0T,
    const float* __restrict__ Wk1T, const float* __restrict__ Wr1T,
    const float* __restrict__ bias1, const int* __restrict__ ids,
    float* __restrict__ H1, float* __restrict__ H0full,
    unsigned* __restrict__ flgA, unsigned* __restrict__ flgB) {
  __shared__ float wk[32][1024];
  __shared__ float hs[NBAT * HIDD];
  __shared__ float z_s[4][64];
  __shared__ float zc[128];
  const int tid  = threadIdx.x;
  const int lane = tid & 63;
  const int w    = tid >> 6;
  const int ccH  = tid >> 7;
  const int part = tid & 127;

  if (blockIdx.x < ABLK) {
    const int hbase = blockIdx.x * 8;
    float4 Wf[16], Wg[16];
    #pragma unroll
    for (int cl = 0; cl < 16; cl++) {
      const int cc = ccH * 16 + cl;
      const int g  = cc >> 3, d = cc & 7;
      const size_t col = (size_t)(g * HIDD + hbase + d);
      Wf[cl] = *(const float4*)(Wr0T + col * HIDD + 4 * part);
      Wg[cl] = *(const float4*)(Wr0T + col * HIDD + 512 + 4 * part);
    }
    float c_reg = 0.f, h_reg = 0.f;
    __syncthreads();

    for (int t = 0; t < SLEN; t++) {
      float pz0 = 0.f, pz1 = 0.f, pz2 = 0.f, pz3 = 0.f;
      int pmk = 0;
      if (tid < 32) {
        const int b = tid >> 3, d = tid & 7;
        const float* zrow = Z0 + (size_t)(b*SLEN + t) * GATE4 + hbase + d;
        pz0 = zrow[0];      pz1 = zrow[HIDD];
        pz2 = zrow[2*HIDD]; pz3 = zrow[3*HIDD];
        pmk = ids[b*SLEN + t];
      }
      float4 ha[NBAT], hb[NBAT];
      if (t > 0) {
        if (tid < ABLK) {
          while (AL(flgA + tid * 16) < (unsigned)t)
            __builtin_amdgcn_s_sleep(4);
        }
        __syncthreads();
        const u64* src = (const u64*)H0full + (size_t)(t - 1) * 2048;
        u64 v[8];
        #pragma unroll
        for (int r = 0; r < 8; r++)
          v[r] = AL(src + tid + (r << 8));
        #pragma unroll
        for (int r = 0; r < 8; r++)
          ((u64*)hs)[tid + (r << 8)] = v[r];
        __syncthreads();
        #pragma unroll
        for (int b = 0; b < NBAT; b++) {
          ha[b] = *(const float4*)(hs + b*HIDD + 4*part);
          hb[b] = *(const float4*)(hs + b*HIDD + 512 + 4*part);
        }
      } else {
        #pragma unroll
        for (int b = 0; b < NBAT; b++) {
          ha[b] = make_float4(0.f, 0.f, 0.f, 0.f);
          hb[b] = make_float4(0.f, 0.f, 0.f, 0.f);
        }
      }
      float a[64];
      #pragma unroll
      for (int cl = 0; cl < 16; cl++)
        #pragma unroll
        for (int b = 0; b < NBAT; b++)
          a[cl*4 + b] = Wf[cl].x*ha[b].x + Wf[cl].y*ha[b].y
                      + Wf[cl].z*ha[b].z + Wf[cl].w*ha[b].w
                      + Wg[cl].x*hb[b].x + Wg[cl].y*hb[b].y
                      + Wg[cl].z*hb[b].z + Wg[cl].w*hb[b].w;
      #pragma unroll
      for (int i = 0; i < 64; i++) a[i] += __shfl_xor(a[i], 32);
      HALVE(1, 0, 32) HALVE(2, 1, 16) HALVE(4, 2, 8) HALVE(8, 3, 4) HALVE(16, 4, 2)
      if (lane < 32) {
        z_s[w][rev5(lane)*2 + 0] = a[0];
        z_s[w][rev5(lane)*2 + 1] = a[1];
      }
      __syncthreads();
      if (tid < 128) {
        const int cc = tid >> 2, b = tid & 3;
        const int cH = cc >> 4, i = ((cc & 15) << 2) | b;
        zc[tid] = z_s[2*cH][i] + z_s[2*cH + 1][i];
      }
      __syncthreads();
      if (tid < 32) {
        const int b = tid >> 3, d = tid & 7;
        const float zi = zc[((0*8 + d) << 2) + b] + pz0;
        const float zf = zc[((1*8 + d) << 2) + b] + pz1;
        const float zg = zc[((2*8 + d) << 2) + b] + pz2;
        const float zo = zc[((3*8 + d) << 2) + b] + pz3;
        const float ig = 1.f / (1.f + expf(-zi));
        const float fg = 1.f / (1.f + expf(-zf));
        const float gg = tanhf(zg);
        const float og = 1.f / (1.f + expf(-zo));
        const float cn = fg * c_reg + ig * gg;
        const float hn = og * tanhf(cn);
        const bool mk = pmk != 0;
        const float ho = mk ? hn : h_reg;
        c_reg = mk ? cn : c_reg;
        h_reg = ho;
        AS(H0full + (size_t)t * (NBAT*HIDD) + b*HIDD + hbase + d, ho);
      }
      if (w == 0) {
        asm volatile("s_waitcnt vmcnt(0)" ::: "memory");
        if (tid == 0)
          AS(flgA + blockIdx.x * 16, (unsigned)(t + 1));
      }
      __syncthreads();
    }
  } else {
    const int bid = blockIdx.x - ABLK;
    const int ub  = bid * 8;
    for (int i = tid; i < 32 * 256; i += 256) {
      const int c2 = i >> 8, k4 = i & 255;
      const size_t col = (size_t)((c2 >> 3) * HIDD + ub + (c2 & 7));
      *(float4*)&wk[c2][k4 * 4] = *(const float4*)(Wk1T + col * HIDD + 4 * k4);
    }
    float4 Rf[16], Rg[16];
    #pragma unroll
    for (int cl = 0; cl < 16; cl++) {
      const int cc = ccH * 16 + cl;
      const int g  = cc >> 3, d = cc & 7;
      const size_t col = (size_t)(g * HIDD + ub + d);
      Rf[cl] = *(const float4*)(Wr1T + col * HIDD + 4 * part);
      Rg[cl] = *(const float4*)(Wr1T + col * HIDD + 512 + 4 * part);
    }
    float pbi = 0.f, pbf = 0.f, pbg = 0.f, pbo = 0.f;
    if (tid < 32) {
      const int d = tid & 7;
      pbi = bias1[0*HIDD + ub + d];
      pbf = bias1[1*HIDD + ub + d];
      pbg = bias1[2*HIDD + ub + d];
      pbo = bias1[3*HIDD + ub + d];
    }
    float c_reg = 0.f, h_reg = 0.f;
    __syncthreads();

    for (int t = 0; t < SLEN; t++) {
      int pmk = 0;
      if (tid < 32) pmk = ids[(tid >> 3) * SLEN + t];
      if (tid < 128) {
        while (AL(flgA + tid * 16) < (unsigned)(t + 1))
          __builtin_amdgcn_s_sleep(4);
      }
      __syncthreads();
      {
        const u64* h0p = (const u64*)H0full + (size_t)t * 2048;
        u64 v[8];
        #pragma unroll
        for (int r = 0; r < 8; r++)
          v[r] = AL(h0p + tid + (r << 8));
        #pragma unroll
        for (int r = 0; r < 8; r++)
          ((u64*)hs)[tid + (r << 8)] = v[r];
      }
      __syncthreads();
      float4 xa[NBAT], xb[NBAT];
      #pragma unroll
      for (int b = 0; b < NBAT; b++) {
        xa[b] = *(const float4*)(hs + b*HIDD + 4*part);
        xb[b] = *(const float4*)(hs + b*HIDD + 512 + 4*part);
      }
      float a[64];
      #pragma unroll
      for (int cl = 0; cl < 16; cl++) {
        const int c2 = ccH * 16 + cl;
        const float4 kf = *(const float4*)&wk[c2][4 * part];
        const float4 kg = *(const float4*)&wk[c2][512 + 4 * part];
        #pragma unroll
        for (int b = 0; b < NBAT; b++) {
          a[cl*4 + b] = kf.x*xa[b].x + kf.y*xa[b].y + kf.z*xa[b].z + kf.w*xa[b].w
                      + kg.x*xb[b].x + kg.y*xb[b].y + kg.z*xb[b].z + kg.w*xb[b].w;
        }
      }
      if (t > 0) {
        if (tid < 128) {
          while (AL(flgB + tid * 16) < (unsigned)t)
            __builtin_amdgcn_s_sleep(4);
        }
        __syncthreads();
        {
          u64 v[8];
          #pragma unroll
          for (int r = 0; r < 8; r++) {
            const int idx = tid + (r << 8);
            const int b = idx >> 9, off = idx & 511;
            v[r] = AL((const u64*)H1 + (size_t)(b*SLEN + t - 1) * 512 + off);
          }
          #pragma unroll
          for (int r = 0; r < 8; r++)
            ((u64*)hs)[tid + (r << 8)] = v[r];
        }
        __syncthreads();
        float4 ya[NBAT], yb[NBAT];
        #pragma unroll
        for (int b = 0; b < NBAT; b++) {
          ya[b] = *(const float4*)(hs + b*HIDD + 4*part);
          yb[b] = *(const float4*)(hs + b*HIDD + 512 + 4*part);
        }
        #pragma unroll
        for (int cl = 0; cl < 16; cl++) {
          #pragma unroll
          for (int b = 0; b < NBAT; b++) {
            a[cl*4 + b] += Rf[cl].x*ya[b].x + Rf[cl].y*ya[b].y
                         + Rf[cl].z*ya[b].z + Rf[cl].w*ya[b].w
                         + Rg[cl].x*yb[b].x + Rg[cl].y*yb[b].y
                         + Rg[cl].z*yb[b].z + Rg[cl].w*yb[b].w;
          }
        }
      }
      #pragma unroll
      for (int i = 0; i < 64; i++) a[i] += __shfl_xor(a[i], 32);
      HALVE(1, 0, 32) HALVE(2, 1, 16) HALVE(4, 2, 8) HALVE(8, 3, 4) HALVE(16, 4, 2)
      if (lane < 32) {
        z_s[w][rev5(lane)*2 + 0] = a[0];
        z_s[w][rev5(lane)*2 + 1] = a[1];
      }
      __syncthreads();
      if (tid < 128) {
        const int cc = tid >> 2, b = tid & 3;
        const int cH = cc >> 4, i = ((cc & 15) << 2) | b;
        zc[tid] = z_s[2*cH][i] + z_s[2*cH + 1][i];
      }
      __syncthreads();
      if (tid < 32) {
        const int b = tid >> 3, d = tid & 7;
        const float zi = zc[((0*8 + d) << 2) + b] + pbi;
        const float zf = zc[((1*8 + d) << 2) + b] + pbf;
        const float zg = zc[((2*8 + d) << 2) + b] + pbg;
        const float zo = zc[((3*8 + d) << 2) + b] + pbo;
        const float ig = 1.f / (1.f + expf(-zi));
        const float fg = 1.f / (1.f + expf(-zf));
        const float gg = tanhf(zg);
        const float og = 1.f / (1.f + expf(-zo));
        const float cn = fg * c_reg + ig * gg;
        const float hn = og * tanhf(cn);
        const bool mk = pmk != 0;
        const float ho = mk ? hn : h_reg;
        c_reg = mk ? cn : c_reg;
        h_reg = ho;
        AS(H1 + (size_t)(b*SLEN + t) * HIDD + ub + d, ho);
      }
      if (w == 0) {
        asm volatile("s_waitcnt vmcnt(0)" ::: "memory");
        if (tid == 0)
          AS(flgB + bid * 16, (unsigned)(t + 1));
      }
      __syncthreads();
    }
  }
}
#undef HALVE

extern "C" void kernel_launch(void* const* d_in, const int* in_sizes, int n_in,
                              void* d_out, int out_size, void* d_ws, size_t ws_size,
                              hipStream_t stream) {
  const int*   ids = (const int*)  d_in[0];
  const float* emb = (const float*)d_in[1];
  const float* Wk0 = (const float*)d_in[2];
  const float* Wr0 = (const float*)d_in[3];
  const float* b0  = (const float*)d_in[4];
  const float* Wk1 = (const float*)d_in[5];
  const float* Wr1 = (const float*)d_in[6];
  const float* b1  = (const float*)d_in[7];
  const float* Wp  = (const float*)d_in[8];
  const float* bp  = (const float*)d_in[9];
  float* out = (float*)d_out;

  // DEAD-before-logits intermediates in the head of d_out.
  float* Z      = out;                  // [2048, 4096]
  float* H1     = out + 8388608;        // [2048, 1024]
  float* Wr0T   = out + 10485760;       // [4096][1024]
  float* Wr1T   = out + 14680064;       // [4096][1024]
  float* Wk1T   = out + 18874368;       // [4096][1024]
  float* H0full = out + 23068672;       // [512][4096]
  // d_ws layout (mfma path): flags 16KB | Phi 2MB | Plo 2MB | Ehi 32.8MB | Elo
  unsigned* flgA = (unsigned*)d_ws;
  unsigned* flgB = (unsigned*)d_ws + 2048;
  char* wsb = (char*)d_ws;
  ushort_t* Phi = (ushort_t*)(wsb + 16384);
  ushort_t* Plo = (ushort_t*)(wsb + 2113536);
  ushort_t* Ehi = (ushort_t*)(wsb + 4210688);
  ushort_t* Elo = (ushort_t*)(wsb + 36978688);
  const size_t WS_NEED = 69746688ull;
  const bool use_mfma = ws_size >= WS_NEED;
  float* P = ((float*)d_ws) + 4096;     // fallback path only (4 MB)

  hipMemsetAsync(d_ws, 0, 16384, stream);  // zero both flag arrays
  if (use_mfma)
    split_bf16_k<<<(VOCAB*EMBD/4 + 255)/256, 256, 0, stream>>>(emb, Ehi, Elo,
                                                              VOCAB*EMBD/4);
  transpose_k<<<dim3(128, 32), 256, 0, stream>>>(Wr0, Wr0T);
  transpose_k<<<dim3(128, 32), 256, 0, stream>>>(Wr1, Wr1T);
  transpose_k<<<dim3(128, 32), 256, 0, stream>>>(Wk1, Wk1T);
  gemm_nn_emb128<<<dim3(32, 16), 256, 0, stream>>>(ids, emb, Wk0, b0, Z);
  lstm_fused<<<ABLK + BBLK, 256, 0, stream>>>(Z, Wr0T, Wk1T, Wr1T, b1, ids,
                                              H1, H0full, flgA, flgB);
  if (use_mfma) {
    gemm_nn_bias_split<<<dim3(8, 32), 256, 0, stream>>>(H1, Wp, bp, Phi, Plo,
                                                        2048, 512, 1024);
    gemm_nt_logits_mfma<<<dim3(250, 32), 256, 0, stream>>>(Phi, Plo, Ehi, Elo,
                                                           ids, out);
  } else {
    gemm_nn_bias<<<dim3(8, 32), 256, 0, stream>>>(H1, Wp, bp, P, 2048, 512, 1024);
    gemm_nt_logits128<<<dim3(250, 16), 256, 0, stream>>>(P, emb, ids, out);
  }
}